// Round 8
// baseline (1856.791 us; speedup 1.0000x reference)
//
#include <hip/hip_runtime.h>

typedef __bf16 bf16;
typedef __attribute__((ext_vector_type(8))) __bf16 bf16x8;
typedef __attribute__((ext_vector_type(4))) __bf16 bf16x4;
typedef __attribute__((ext_vector_type(2))) __bf16 bf16x2;
typedef __attribute__((ext_vector_type(4))) float f32x4;

// ---------------- narrow MFMA GEMM: 128x128 block tile (for ncols <= 128)
__global__ __launch_bounds__(256) void gemm_mfma(
    const bf16* __restrict__ A, int lda,
    const bf16* __restrict__ Bt, int Kd,
    const float* __restrict__ bias,
    bf16* __restrict__ Cb, float* __restrict__ Cf, int ldc,
    int R, int ncols, int relu,
    const float* __restrict__ scale_ptr)
{
    __shared__ bf16 Bs[128 * 40];
    const int tid  = threadIdx.x;
    const int wid  = tid >> 6;
    const int lane = tid & 63;
    const int m    = lane & 15;
    const int quad = lane >> 4;

    const long row0    = (long)blockIdx.x * 128 + wid * 32;
    const int  colbase = blockIdx.y * 128;

    f32x4 acc[2][8];
#pragma unroll
    for (int rt = 0; rt < 2; ++rt)
#pragma unroll
        for (int ct = 0; ct < 8; ++ct)
            acc[rt][ct] = f32x4{0.f, 0.f, 0.f, 0.f};

    const bf16* Aptr[2];
#pragma unroll
    for (int rt = 0; rt < 2; ++rt) {
        long r = row0 + rt * 16 + m;
        if (r > (long)R - 1) r = (long)R - 1;
        Aptr[rt] = A + r * (long)lda + quad * 8;
    }
    const bf16* Bstage = Bt + ((long)colbase + (tid >> 2)) * Kd + (tid & 3) * 8;

    for (int k = 0; k < Kd; k += 32) {
        __syncthreads();
        {
            int c = tid >> 2, kk = (tid & 3) * 8;
            *(bf16x8*)&Bs[c * 40 + kk]        = *(const bf16x8*)(Bstage + k);
            *(bf16x8*)&Bs[(c + 64) * 40 + kk] = *(const bf16x8*)(Bstage + (long)64 * Kd + k);
        }
        __syncthreads();
        bf16x8 a0 = *(const bf16x8*)(Aptr[0] + k);
        bf16x8 a1 = *(const bf16x8*)(Aptr[1] + k);
#pragma unroll
        for (int ct = 0; ct < 8; ++ct) {
            bf16x8 b = *(const bf16x8*)&Bs[(ct * 16 + m) * 40 + quad * 8];
            acc[0][ct] = __builtin_amdgcn_mfma_f32_16x16x32_bf16(a0, b, acc[0][ct], 0, 0, 0);
            acc[1][ct] = __builtin_amdgcn_mfma_f32_16x16x32_bf16(a1, b, acc[1][ct], 0, 0, 0);
        }
    }

    const float scale = scale_ptr ? *scale_ptr : 1.f;
#pragma unroll
    for (int ct = 0; ct < 8; ++ct) {
        int col = colbase + ct * 16 + m;
        if (col >= ncols) continue;
        float bv = bias ? bias[col] : 0.f;
#pragma unroll
        for (int rt = 0; rt < 2; ++rt) {
#pragma unroll
            for (int r = 0; r < 4; ++r) {
                long row = row0 + rt * 16 + quad * 4 + r;
                if (row < R) {
                    float v = acc[rt][ct][r] * scale + bv;
                    if (relu && v < 0.f) v = 0.f;
                    if (Cf) Cf[row * (long)ldc + col] = v;
                    else    Cb[row * (long)ldc + col] = (bf16)v;
                }
            }
        }
    }
}

// ---------------- wide MFMA GEMM: 128x256 block tile (for ncols >= 129)
// 4 waves x 32 rows x 256 cols: 32 MFMA per 2-barrier K-step; halves A re-fetch vs narrow.
__global__ __launch_bounds__(256) void gemm_mfma_w(
    const bf16* __restrict__ A, int lda,
    const bf16* __restrict__ Bt, int Kd,
    const float* __restrict__ bias,
    bf16* __restrict__ Cb, float* __restrict__ Cf, int ldc,
    int R, int ncols, int relu,
    const float* __restrict__ scale_ptr)
{
    __shared__ bf16 Bs[256 * 40];   // 20 KB
    const int tid  = threadIdx.x;
    const int wid  = tid >> 6;
    const int lane = tid & 63;
    const int m    = lane & 15;
    const int quad = lane >> 4;

    const long row0    = (long)blockIdx.x * 128 + wid * 32;
    const int  colbase = blockIdx.y * 256;

    f32x4 acc[2][16];
#pragma unroll
    for (int rt = 0; rt < 2; ++rt)
#pragma unroll
        for (int ct = 0; ct < 16; ++ct)
            acc[rt][ct] = f32x4{0.f, 0.f, 0.f, 0.f};

    const bf16* Aptr[2];
#pragma unroll
    for (int rt = 0; rt < 2; ++rt) {
        long r = row0 + rt * 16 + m;
        if (r > (long)R - 1) r = (long)R - 1;
        Aptr[rt] = A + r * (long)lda + quad * 8;
    }
    const bf16* Bstage = Bt + ((long)colbase + (tid >> 2)) * Kd + (tid & 3) * 8;

    for (int k = 0; k < Kd; k += 32) {
        __syncthreads();
        {
            int c = tid >> 2, kk = (tid & 3) * 8;
#pragma unroll
            for (int cc = 0; cc < 4; ++cc)
                *(bf16x8*)&Bs[(c + cc * 64) * 40 + kk] =
                    *(const bf16x8*)(Bstage + (long)(cc * 64) * Kd + k);
        }
        __syncthreads();
        bf16x8 a0 = *(const bf16x8*)(Aptr[0] + k);
        bf16x8 a1 = *(const bf16x8*)(Aptr[1] + k);
#pragma unroll
        for (int ct = 0; ct < 16; ++ct) {
            bf16x8 b = *(const bf16x8*)&Bs[(ct * 16 + m) * 40 + quad * 8];
            acc[0][ct] = __builtin_amdgcn_mfma_f32_16x16x32_bf16(a0, b, acc[0][ct], 0, 0, 0);
            acc[1][ct] = __builtin_amdgcn_mfma_f32_16x16x32_bf16(a1, b, acc[1][ct], 0, 0, 0);
        }
    }

    const float scale = scale_ptr ? *scale_ptr : 1.f;
#pragma unroll
    for (int ct = 0; ct < 16; ++ct) {
        int col = colbase + ct * 16 + m;
        if (col >= ncols) continue;
        float bv = bias ? bias[col] : 0.f;
#pragma unroll
        for (int rt = 0; rt < 2; ++rt) {
#pragma unroll
            for (int r = 0; r < 4; ++r) {
                long row = row0 + rt * 16 + quad * 4 + r;
                if (row < R) {
                    float v = acc[rt][ct][r] * scale + bv;
                    if (relu && v < 0.f) v = 0.f;
                    if (Cf) Cf[row * (long)ldc + col] = v;
                    else    Cb[row * (long)ldc + col] = (bf16)v;
                }
            }
        }
    }
}

// ---------------- weight transpose + cast
__global__ void transpose_f2b(const float* __restrict__ in, int K, int ncols,
                              bf16* __restrict__ out, int Kd, int npad)
{
    long idx = (long)blockIdx.x * 256 + threadIdx.x;
    long total = (long)npad * Kd;
    if (idx >= total) return;
    int k = (int)(idx % Kd);
    int n = (int)(idx / Kd);
    float v = (k < K && n < ncols) ? in[(long)k * ncols + n] : 0.f;
    out[idx] = (bf16)v;
}

__global__ void transpose_M(const float* __restrict__ M, bf16* __restrict__ out)
{
    int idx = blockIdx.x * 256 + threadIdx.x;
    int k = idx & 127, n = idx >> 7;
    float v = (k < 100 && n < 100) ? M[k * 100 + n] : 0.f;
    out[idx] = (bf16)v;
}

__global__ void cast_f2b(const float* __restrict__ in, long total, bf16* __restrict__ out)
{
    long idx = (long)blockIdx.x * 256 + threadIdx.x;
    if (idx < total) out[idx] = (bf16)in[idx];
}

// ---------------- CSR build
__global__ void hist_kernel(const int* __restrict__ dst, int E, int* __restrict__ cnt)
{
    int e = blockIdx.x * 256 + threadIdx.x;
    if (e < E) atomicAdd(&cnt[dst[e]], 1);
}

__global__ __launch_bounds__(1024) void scan_kernel(const int* __restrict__ cnt, int n,
                                                    int* __restrict__ rowptr,
                                                    int* __restrict__ cursor,
                                                    float* __restrict__ dis)
{
    __shared__ int sdata[1024];
    __shared__ int s_off;
    int t = threadIdx.x;
    if (t == 0) s_off = 0;
    __syncthreads();
    for (int base = 0; base < n; base += 1024) {
        int i = base + t;
        int v = (i < n) ? cnt[i] : 0;
        sdata[t] = v;
        __syncthreads();
        for (int d = 1; d < 1024; d <<= 1) {
            int x = (t >= d) ? sdata[t - d] : 0;
            __syncthreads();
            sdata[t] += x;
            __syncthreads();
        }
        int inc = sdata[t];
        int off = s_off;
        if (i < n) {
            int excl = off + inc - v;
            rowptr[i] = excl;
            cursor[i] = excl;
            dis[i] = rsqrtf((float)(v + 1));
        }
        __syncthreads();
        if (t == 1023) s_off = off + inc;
        __syncthreads();
    }
    if (t == 0) rowptr[n] = s_off;
}

__global__ void scatter_kernel(const int* __restrict__ src, const int* __restrict__ dst,
                               int E, int* __restrict__ cursor, int* __restrict__ colidx)
{
    int e = blockIdx.x * 256 + threadIdx.x;
    if (e < E) {
        int d = dst[e];
        int pos = atomicAdd(&cursor[d], 1);
        colidx[pos] = src[e];
    }
}

// ---------------- GCN aggregation: one wave per dst node, bf16 h (halved gather bytes)
__global__ __launch_bounds__(256) void agg_kernel(
    const bf16* __restrict__ h, const int* __restrict__ rowptr,
    const int* __restrict__ colidx, const float* __restrict__ dis,
    const float* __restrict__ cb, bf16* __restrict__ out, int ldc, int R)
{
    int wid = threadIdx.x >> 6, lane = threadIdx.x & 63;
    int i = blockIdx.x * 4 + wid;
    if (i >= R) return;
    float disi = dis[i];
    bf16x4 hv = *(const bf16x4*)(h + (long)i * 256 + lane * 4);
    float acc[4];
#pragma unroll
    for (int j = 0; j < 4; ++j) acc[j] = (float)hv[j] * disi;  // self loop
    int e0 = rowptr[i], e1 = rowptr[i + 1];
    for (int e = e0; e < e1; ++e) {
        int s = colidx[e];
        float w = dis[s];
        bf16x4 hs = *(const bf16x4*)(h + (long)s * 256 + lane * 4);
#pragma unroll
        for (int j = 0; j < 4; ++j) acc[j] += (float)hs[j] * w;
    }
    bf16x4 o;
#pragma unroll
    for (int j = 0; j < 4; ++j) {
        float v = acc[j] * disi + cb[lane * 4 + j];
        if (v < 0.f) v = 0.f;
        o[j] = (bf16)v;
    }
    *(bf16x4*)(out + (long)i * ldc + lane * 4) = o;
}

// ---------------- column sums of U,V
__global__ void colsum_kernel(const bf16* __restrict__ t, int ld, int R, float* __restrict__ cs)
{
    int c = threadIdx.x;
    if (c >= 200) return;
    int i0 = blockIdx.x * 256;
    int i1 = i0 + 256; if (i1 > R) i1 = R;
    float s = 0.f;
    for (int i = i0; i < i1; ++i) s += (float)t[(long)i * ld + c];
    atomicAdd(&cs[c], s);
}

__global__ void nf_kernel(const float* __restrict__ cs, float* __restrict__ scale, int R)
{
    __shared__ float s[128];
    int t = threadIdx.x;
    float v = (t < 100) ? cs[t] * cs[100 + t] : 0.f;
    s[t] = v;
    __syncthreads();
    for (int d = 64; d > 0; d >>= 1) {
        if (t < d) s[t] += s[t + d];
        __syncthreads();
    }
    if (t == 0) scale[0] = 1.0f / (s[0] / (float)R + 1e-6f);
}

// ---------------- M = V^T Z via MFMA, two-stage, no atomics
#define VTZ_BLOCKS 128
__global__ __launch_bounds__(256) void vtz_mfma(const bf16* __restrict__ t, int ld, int R,
                                                float* __restrict__ Mpart)
{
    __shared__ bf16 Vt[112 * 72];
    __shared__ bf16 Zt[112 * 72];
    const int tid  = threadIdx.x;
    const int wid  = tid >> 6;
    const int lane = tid & 63;
    const int m    = lane & 15;
    const int quad = lane >> 4;

    for (int idx = tid; idx < 12 * 64; idx += 256) {
        int c = 100 + (idx >> 6), r = idx & 63;
        Vt[c * 72 + r] = (bf16)0.f;
        Zt[c * 72 + r] = (bf16)0.f;
    }

    f32x4 acc[2][7];
#pragma unroll
    for (int rt = 0; rt < 2; ++rt)
#pragma unroll
        for (int ct = 0; ct < 7; ++ct)
            acc[rt][ct] = f32x4{0.f, 0.f, 0.f, 0.f};

    for (long base = (long)blockIdx.x * 64; base < R; base += (long)gridDim.x * 64) {
        __syncthreads();
        for (int idx = tid; idx < 50 * 64; idx += 256) {
            int r = idx / 50, c2 = (idx - r * 50) * 2;
            bf16x2 v2 = bf16x2{(bf16)0.f, (bf16)0.f};
            bf16x2 z2 = bf16x2{(bf16)0.f, (bf16)0.f};
            if (base + r < R) {
                v2 = *(const bf16x2*)(t + (base + r) * ld + 100 + c2);
                z2 = *(const bf16x2*)(t + (base + r) * ld + 200 + c2);
            }
            Vt[c2 * 72 + r] = v2[0]; Vt[(c2 + 1) * 72 + r] = v2[1];
            Zt[c2 * 72 + r] = z2[0]; Zt[(c2 + 1) * 72 + r] = z2[1];
        }
        __syncthreads();
#pragma unroll
        for (int ks = 0; ks < 2; ++ks) {
            int k0 = ks * 32 + quad * 8;
            bf16x8 b[7];
#pragma unroll
            for (int ct = 0; ct < 7; ++ct)
                b[ct] = *(const bf16x8*)&Zt[(ct * 16 + m) * 72 + k0];
#pragma unroll
            for (int rt = 0; rt < 2; ++rt) {
                int tr = wid + rt * 4;
                if (tr >= 7) continue;
                bf16x8 a = *(const bf16x8*)&Vt[(tr * 16 + m) * 72 + k0];
#pragma unroll
                for (int ct = 0; ct < 7; ++ct)
                    acc[rt][ct] = __builtin_amdgcn_mfma_f32_16x16x32_bf16(a, b[ct], acc[rt][ct], 0, 0, 0);
            }
        }
    }

    float* out = Mpart + (long)blockIdx.x * 10000;
#pragma unroll
    for (int rt = 0; rt < 2; ++rt) {
        int tr = wid + rt * 4;
        if (tr >= 7) continue;
#pragma unroll
        for (int ct = 0; ct < 7; ++ct) {
            int b = ct * 16 + m;
            if (b >= 100) continue;
#pragma unroll
            for (int r = 0; r < 4; ++r) {
                int a = tr * 16 + quad * 4 + r;
                if (a < 100) out[a * 100 + b] = acc[rt][ct][r];
            }
        }
    }
}

__global__ void vtz_reduce(const float* __restrict__ Mpart, float* __restrict__ M)
{
    int idx = blockIdx.x * 256 + threadIdx.x;
    if (idx >= 10000) return;
    float s = 0.f;
    for (int b = 0; b < VTZ_BLOCKS; ++b) s += Mpart[(long)b * 10000 + idx];
    M[idx] = s;
}

// ---------------- batch norm (y fp32)
__global__ void bn_stats(const float* __restrict__ y, int R, float* __restrict__ sums)
{
    int c = threadIdx.x;
    int i0 = blockIdx.x * 256;
    int i1 = i0 + 256; if (i1 > R) i1 = R;
    float s = 0.f, s2 = 0.f;
    for (int i = i0; i < i1; ++i) {
        float v = y[(long)i * 256 + c];
        s += v; s2 += v * v;
    }
    atomicAdd(&sums[c], s);
    atomicAdd(&sums[256 + c], s2);
}

__global__ void bn_finalize(const float* __restrict__ sums, const float* __restrict__ g,
                            const float* __restrict__ bt, int R, float* __restrict__ ab)
{
    int c = threadIdx.x;
    float mean = sums[c] / (float)R;
    float var  = sums[256 + c] / (float)R - mean * mean;
    if (var < 0.f) var = 0.f;
    float a = g[c] * rsqrtf(var + 1e-5f);
    ab[c] = a;
    ab[256 + c] = bt[c] - mean * a;
}

__global__ void bn_apply(const float* __restrict__ y, const float* __restrict__ ab,
                         int total, bf16* __restrict__ x)
{
    int idx = blockIdx.x * 256 + threadIdx.x;
    if (idx < total) {
        int c = idx & 255;
        x[idx] = (bf16)(y[idx] * ab[c] + ab[256 + c]);
    }
}

// =====================================================================================
extern "C" void kernel_launch(void* const* d_in, const int* in_sizes, int n_in,
                              void* d_out, int out_size, void* d_ws, size_t ws_size,
                              hipStream_t stream)
{
    (void)n_in; (void)out_size; (void)ws_size;
    const int N = in_sizes[0] / 128;       // 50000
    const int E = in_sizes[1] / 2;         // 800000

    const float* x0 = (const float*)d_in[0];
    const int*  ei   = (const int*)d_in[1];
    const int*  esrc = ei;
    const int*  edst = ei + E;
    const float *cw[3], *cbv[3], *aw[3], *abv[3], *rw[3], *rbv[3];
    for (int l = 0; l < 3; ++l) {
        cw[l]  = (const float*)d_in[2 + 6 * l];
        cbv[l] = (const float*)d_in[3 + 6 * l];
        aw[l]  = (const float*)d_in[4 + 6 * l];
        abv[l] = (const float*)d_in[5 + 6 * l];
        rw[l]  = (const float*)d_in[6 + 6 * l];
        rbv[l] = (const float*)d_in[7 + 6 * l];
    }
    const float* g[2]   = {(const float*)d_in[20], (const float*)d_in[22]};
    const float* btb[2] = {(const float*)d_in[21], (const float*)d_in[23]};

    // ---- workspace carve (~163 MB, below proven-good 166.5 MB) ----
    char* p = (char*)d_ws;
    auto carve = [&](size_t bytes) -> char* {
        char* r = p; p += (bytes + 255) & ~(size_t)255; return r;
    };
    int*   cnt    = (int*)carve((size_t)N * 4);
    int*   rowptr = (int*)carve((size_t)(N + 1) * 4);
    int*   cursor = (int*)carve((size_t)N * 4);
    int*   colidx = (int*)carve((size_t)E * 4);
    float* dis    = (float*)carve((size_t)N * 4);
    float* Mbuf   = (float*)carve(100 * 100 * 4);
    float* Mpart  = (float*)carve((size_t)VTZ_BLOCKS * 10000 * 4);
    float* csbuf  = (float*)carve(200 * 4);
    float* scale  = (float*)carve(256);
    float* bnsum  = (float*)carve(512 * 4);
    float* bnab   = (float*)carve(512 * 4);
    bf16*  MT     = (bf16*)carve(128 * 128 * 2);
    bf16*  cwT[3], *awT[3], *rwT[3];
    int din[3] = {128, 256, 256};
    int dou[3] = {256, 256, 128};
    for (int l = 0; l < 3; ++l) {
        cwT[l] = (bf16*)carve((size_t)256 * din[l] * 2);
        awT[l] = (bf16*)carve((size_t)512 * din[l] * 2);
        rwT[l] = (bf16*)carve((size_t)dou[l] * 480 * 2);
    }
    bf16*  xbf  = (bf16*)carve((size_t)N * 256 * 2);        // current x (bf16)
    float* hbuf = (float*)carve((size_t)N * 256 * 4);       // y (fp32); hb (bf16 h) aliases it
    bf16*  hb   = (bf16*)hbuf;                              // h bf16 — dead before y written
    bf16*  tbuf = (bf16*)carve((size_t)N * 300 * 2);        // U|V|Z (ld=300)
    bf16*  xcat = (bf16*)carve(((size_t)N * 456 + 32) * 2); // [res|T|xloc], ld=456

    // ---- CSR build ----
    hipMemsetAsync(cnt, 0, (size_t)N * 4, stream);
    hist_kernel<<<(E + 255) / 256, 256, 0, stream>>>(edst, E, cnt);
    scan_kernel<<<1, 1024, 0, stream>>>(cnt, N, rowptr, cursor, dis);
    scatter_kernel<<<(E + 255) / 256, 256, 0, stream>>>(esrc, edst, E, cursor, colidx);

    // ---- weight transposes + x0 cast ----
    for (int l = 0; l < 3; ++l) {
        transpose_f2b<<<((long)256 * din[l] + 255) / 256, 256, 0, stream>>>(
            cw[l], din[l], 256, cwT[l], din[l], 256);
        transpose_f2b<<<((long)512 * din[l] + 255) / 256, 256, 0, stream>>>(
            aw[l], din[l], 400, awT[l], din[l], 512);
        transpose_f2b<<<((long)dou[l] * 480 + 255) / 256, 256, 0, stream>>>(
            rw[l], 456, dou[l], rwT[l], 480, dou[l]);
    }
    cast_f2b<<<((long)N * 128 + 255) / 256, 256, 0, stream>>>(x0, (long)N * 128, xbf);

    int lda = 128;
    const unsigned gx = (unsigned)((N + 127) / 128);

    for (int l = 0; l < 3; ++l) {
        // 1) h = x @ cw -> hb (bf16; bias/relu deferred to agg)  [wide: 256 cols, gy=1]
        gemm_mfma_w<<<dim3(gx, 1), 256, 0, stream>>>(xbf, lda, cwT[l], din[l], nullptr,
                                                     hb, nullptr, 256, N, 256, 0, nullptr);
        // 2) U|V|Z = relu(x @ aw[:,0:300] + ab[0:300]) -> tbuf  [wide: gy=2]
        gemm_mfma_w<<<dim3(gx, 2), 256, 0, stream>>>(xbf, lda, awT[l], din[l], abv[l],
                                                     tbuf, nullptr, 300, N, 300, 1, nullptr);
        // 3) T = relu(x @ aw[:,300:400] + ab[300:]) -> xcat cols 100..199  [narrow]
        gemm_mfma<<<dim3(gx, 1), 256, 0, stream>>>(xbf, lda, awT[l] + (long)300 * din[l], din[l],
                                                   abv[l] + 300,
                                                   xcat + 100, nullptr, 456, N, 100, 1, nullptr);
        // 4) colsums + nf
        hipMemsetAsync(csbuf, 0, 200 * 4, stream);
        colsum_kernel<<<(N + 255) / 256, 256, 0, stream>>>(tbuf, 300, N, csbuf);
        nf_kernel<<<1, 128, 0, stream>>>(csbuf, scale, N);
        // 5) M = V^T Z (MFMA two-stage) ; transpose/cast to MT
        vtz_mfma<<<VTZ_BLOCKS, 256, 0, stream>>>(tbuf, 300, N, Mpart);
        vtz_reduce<<<40, 256, 0, stream>>>(Mpart, Mbuf);
        transpose_M<<<64, 256, 0, stream>>>(Mbuf, MT);
        // 6) res = scale * (U @ M) -> xcat cols 0..99  [narrow; Kd=128 over zero-padded MT]
        gemm_mfma<<<dim3(gx, 1), 256, 0, stream>>>(tbuf, 300, MT, 128, nullptr,
                                                   xcat, nullptr, 456, N, 100, 0, scale);
        // 7) x_local = relu(agg + cb) -> xcat cols 200..455  (reads hb, dead after this)
        agg_kernel<<<(N + 3) / 4, 256, 0, stream>>>(hb, rowptr, colidx, dis, cbv[l],
                                                    xcat + 200, 456, N);
        // 8) readout (Kd=480: cols 456..479 junk x zero weight rows = 0)
        if (l < 2) {
            gemm_mfma_w<<<dim3(gx, 1), 256, 0, stream>>>(xcat, 456, rwT[l], 480, rbv[l],
                                                         nullptr, hbuf, 256, N, 256, 1, nullptr);
            hipMemsetAsync(bnsum, 0, 512 * 4, stream);
            bn_stats<<<(N + 255) / 256, 256, 0, stream>>>(hbuf, N, bnsum);
            bn_finalize<<<1, 256, 0, stream>>>(bnsum, g[l], btb[l], N, bnab);
            bn_apply<<<((long)N * 256 + 255) / 256, 256, 0, stream>>>(hbuf, bnab, N * 256, xbf);
            lda = 256;
        } else {
            gemm_mfma<<<dim3(gx, 1), 256, 0, stream>>>(xcat, 456, rwT[l], 480, rbv[l],
                                                       nullptr, (float*)d_out, 128, N, 128, 0, nullptr);
        }
    }
}

// Round 9
// 1450.390 us; speedup vs baseline: 1.2802x; 1.2802x over previous
//
#include <hip/hip_runtime.h>

typedef __bf16 bf16;
typedef __attribute__((ext_vector_type(8))) __bf16 bf16x8;
typedef __attribute__((ext_vector_type(4))) __bf16 bf16x4;
typedef __attribute__((ext_vector_type(2))) __bf16 bf16x2;
typedef __attribute__((ext_vector_type(4))) float f32x4;

// ---------------- narrow MFMA GEMM: 128x128 block tile
__global__ __launch_bounds__(256) void gemm_mfma(
    const bf16* __restrict__ A, int lda,
    const bf16* __restrict__ Bt, int Kd,
    const float* __restrict__ bias,
    bf16* __restrict__ Cb, float* __restrict__ Cf, int ldc,
    int R, int ncols, int relu,
    const float* __restrict__ scale_ptr)
{
    __shared__ bf16 Bs[128 * 40];
    const int tid  = threadIdx.x;
    const int wid  = tid >> 6;
    const int lane = tid & 63;
    const int m    = lane & 15;
    const int quad = lane >> 4;

    const long row0    = (long)blockIdx.x * 128 + wid * 32;
    const int  colbase = blockIdx.y * 128;

    f32x4 acc[2][8];
#pragma unroll
    for (int rt = 0; rt < 2; ++rt)
#pragma unroll
        for (int ct = 0; ct < 8; ++ct)
            acc[rt][ct] = f32x4{0.f, 0.f, 0.f, 0.f};

    const bf16* Aptr[2];
#pragma unroll
    for (int rt = 0; rt < 2; ++rt) {
        long r = row0 + rt * 16 + m;
        if (r > (long)R - 1) r = (long)R - 1;
        Aptr[rt] = A + r * (long)lda + quad * 8;
    }
    const bf16* Bstage = Bt + ((long)colbase + (tid >> 2)) * Kd + (tid & 3) * 8;

    for (int k = 0; k < Kd; k += 32) {
        __syncthreads();
        {
            int c = tid >> 2, kk = (tid & 3) * 8;
            *(bf16x8*)&Bs[c * 40 + kk]        = *(const bf16x8*)(Bstage + k);
            *(bf16x8*)&Bs[(c + 64) * 40 + kk] = *(const bf16x8*)(Bstage + (long)64 * Kd + k);
        }
        __syncthreads();
        bf16x8 a0 = *(const bf16x8*)(Aptr[0] + k);
        bf16x8 a1 = *(const bf16x8*)(Aptr[1] + k);
#pragma unroll
        for (int ct = 0; ct < 8; ++ct) {
            bf16x8 b = *(const bf16x8*)&Bs[(ct * 16 + m) * 40 + quad * 8];
            acc[0][ct] = __builtin_amdgcn_mfma_f32_16x16x32_bf16(a0, b, acc[0][ct], 0, 0, 0);
            acc[1][ct] = __builtin_amdgcn_mfma_f32_16x16x32_bf16(a1, b, acc[1][ct], 0, 0, 0);
        }
    }

    const float scale = scale_ptr ? *scale_ptr : 1.f;
#pragma unroll
    for (int ct = 0; ct < 8; ++ct) {
        int col = colbase + ct * 16 + m;
        if (col >= ncols) continue;
        float bv = bias ? bias[col] : 0.f;
#pragma unroll
        for (int rt = 0; rt < 2; ++rt) {
#pragma unroll
            for (int r = 0; r < 4; ++r) {
                long row = row0 + rt * 16 + quad * 4 + r;
                if (row < R) {
                    float v = acc[rt][ct][r] * scale + bv;
                    if (relu && v < 0.f) v = 0.f;
                    if (Cf) Cf[row * (long)ldc + col] = v;
                    else    Cb[row * (long)ldc + col] = (bf16)v;
                }
            }
        }
    }
}

// ---------------- weight transpose + cast
__global__ void transpose_f2b(const float* __restrict__ in, int K, int ncols,
                              bf16* __restrict__ out, int Kd, int npad)
{
    long idx = (long)blockIdx.x * 256 + threadIdx.x;
    long total = (long)npad * Kd;
    if (idx >= total) return;
    int k = (int)(idx % Kd);
    int n = (int)(idx / Kd);
    float v = (k < K && n < ncols) ? in[(long)k * ncols + n] : 0.f;
    out[idx] = (bf16)v;
}

__global__ void transpose_M(const float* __restrict__ M, bf16* __restrict__ out)
{
    int idx = blockIdx.x * 256 + threadIdx.x;
    int k = idx & 127, n = idx >> 7;
    float v = (k < 100 && n < 100) ? M[k * 100 + n] : 0.f;
    out[idx] = (bf16)v;
}

__global__ void cast_f2b(const float* __restrict__ in, long total, bf16* __restrict__ out)
{
    long idx = (long)blockIdx.x * 256 + threadIdx.x;
    if (idx < total) out[idx] = (bf16)in[idx];
}

// ---------------- CSR build: hist + 3-phase parallel scan + scatter
__global__ void hist_kernel(const int* __restrict__ dst, int E, int* __restrict__ cnt)
{
    int e = blockIdx.x * 256 + threadIdx.x;
    if (e < E) atomicAdd(&cnt[dst[e]], 1);
}

// phase A: per-chunk sums (1024 elems per block)
__global__ __launch_bounds__(1024) void scanA_kernel(const int* __restrict__ cnt, int n,
                                                     int* __restrict__ csum)
{
    __shared__ int sdata[1024];
    int t = threadIdx.x;
    int i = blockIdx.x * 1024 + t;
    sdata[t] = (i < n) ? cnt[i] : 0;
    __syncthreads();
    for (int d = 512; d > 0; d >>= 1) {
        if (t < d) sdata[t] += sdata[t + d];
        __syncthreads();
    }
    if (t == 0) csum[blockIdx.x] = sdata[0];
}

// phase B: exclusive scan of nchunks sums (single small block; nchunks <= 64)
__global__ void scanB_kernel(int* __restrict__ csum, int nchunks, int n, int* __restrict__ rowptr)
{
    if (threadIdx.x == 0) {
        int run = 0;
        for (int b = 0; b < nchunks; ++b) {
            int v = csum[b];
            csum[b] = run;
            run += v;
        }
        rowptr[n] = run;
    }
}

// phase C: per-chunk exclusive scan + chunk offset; writes rowptr/cursor/dis
__global__ __launch_bounds__(1024) void scanC_kernel(const int* __restrict__ cnt, int n,
                                                     const int* __restrict__ csum,
                                                     int* __restrict__ rowptr,
                                                     int* __restrict__ cursor,
                                                     float* __restrict__ dis)
{
    __shared__ int sdata[1024];
    int t = threadIdx.x;
    int i = blockIdx.x * 1024 + t;
    int v = (i < n) ? cnt[i] : 0;
    sdata[t] = v;
    __syncthreads();
    for (int d = 1; d < 1024; d <<= 1) {
        int x = (t >= d) ? sdata[t - d] : 0;
        __syncthreads();
        sdata[t] += x;
        __syncthreads();
    }
    if (i < n) {
        int excl = csum[blockIdx.x] + sdata[t] - v;
        rowptr[i] = excl;
        cursor[i] = excl;
        dis[i] = rsqrtf((float)(v + 1));   // deg = in-degree + self-loop
    }
}

__global__ void scatter_kernel(const int* __restrict__ src, const int* __restrict__ dst,
                               int E, int* __restrict__ cursor, int* __restrict__ colidx)
{
    int e = blockIdx.x * 256 + threadIdx.x;
    if (e < E) {
        int d = dst[e];
        int pos = atomicAdd(&cursor[d], 1);
        colidx[pos] = src[e];
    }
}

// ---------------- GCN aggregation: one wave per dst node, bf16 h, 4x edge unroll for MLP
__global__ __launch_bounds__(256) void agg_kernel(
    const bf16* __restrict__ h, const int* __restrict__ rowptr,
    const int* __restrict__ colidx, const float* __restrict__ dis,
    const float* __restrict__ cb, bf16* __restrict__ out, int ldc, int R)
{
    int wid = threadIdx.x >> 6, lane = threadIdx.x & 63;
    int i = blockIdx.x * 4 + wid;
    if (i >= R) return;
    float disi = dis[i];
    bf16x4 hv = *(const bf16x4*)(h + (long)i * 256 + lane * 4);
    float acc[4];
#pragma unroll
    for (int j = 0; j < 4; ++j) acc[j] = (float)hv[j] * disi;  // self loop
    int e0 = rowptr[i], e1 = rowptr[i + 1];
    int e = e0;
    for (; e + 3 < e1; e += 4) {
        int s0 = colidx[e], s1 = colidx[e + 1], s2 = colidx[e + 2], s3 = colidx[e + 3];
        float w0 = dis[s0], w1 = dis[s1], w2 = dis[s2], w3 = dis[s3];
        bf16x4 h0 = *(const bf16x4*)(h + (long)s0 * 256 + lane * 4);
        bf16x4 h1 = *(const bf16x4*)(h + (long)s1 * 256 + lane * 4);
        bf16x4 h2 = *(const bf16x4*)(h + (long)s2 * 256 + lane * 4);
        bf16x4 h3 = *(const bf16x4*)(h + (long)s3 * 256 + lane * 4);
#pragma unroll
        for (int j = 0; j < 4; ++j)
            acc[j] += (float)h0[j] * w0 + (float)h1[j] * w1
                    + (float)h2[j] * w2 + (float)h3[j] * w3;
    }
    for (; e < e1; ++e) {
        int s = colidx[e];
        float w = dis[s];
        bf16x4 hs = *(const bf16x4*)(h + (long)s * 256 + lane * 4);
#pragma unroll
        for (int j = 0; j < 4; ++j) acc[j] += (float)hs[j] * w;
    }
    bf16x4 o;
#pragma unroll
    for (int j = 0; j < 4; ++j) {
        float v = acc[j] * disi + cb[lane * 4 + j];
        if (v < 0.f) v = 0.f;
        o[j] = (bf16)v;
    }
    *(bf16x4*)(out + (long)i * ldc + lane * 4) = o;
}

// ---------------- column sums of U,V
__global__ void colsum_kernel(const bf16* __restrict__ t, int ld, int R, float* __restrict__ cs)
{
    int c = threadIdx.x;
    if (c >= 200) return;
    int i0 = blockIdx.x * 256;
    int i1 = i0 + 256; if (i1 > R) i1 = R;
    float s = 0.f;
    for (int i = i0; i < i1; ++i) s += (float)t[(long)i * ld + c];
    atomicAdd(&cs[c], s);
}

__global__ void nf_kernel(const float* __restrict__ cs, float* __restrict__ scale, int R)
{
    __shared__ float s[128];
    int t = threadIdx.x;
    float v = (t < 100) ? cs[t] * cs[100 + t] : 0.f;
    s[t] = v;
    __syncthreads();
    for (int d = 64; d > 0; d >>= 1) {
        if (t < d) s[t] += s[t + d];
        __syncthreads();
    }
    if (t == 0) scale[0] = 1.0f / (s[0] / (float)R + 1e-6f);
}

// ---------------- M = V^T Z via MFMA, two-stage, no atomics
#define VTZ_BLOCKS 128
__global__ __launch_bounds__(256) void vtz_mfma(const bf16* __restrict__ t, int ld, int R,
                                                float* __restrict__ Mpart)
{
    __shared__ bf16 Vt[112 * 72];
    __shared__ bf16 Zt[112 * 72];
    const int tid  = threadIdx.x;
    const int wid  = tid >> 6;
    const int lane = tid & 63;
    const int m    = lane & 15;
    const int quad = lane >> 4;

    for (int idx = tid; idx < 12 * 64; idx += 256) {
        int c = 100 + (idx >> 6), r = idx & 63;
        Vt[c * 72 + r] = (bf16)0.f;
        Zt[c * 72 + r] = (bf16)0.f;
    }

    f32x4 acc[2][7];
#pragma unroll
    for (int rt = 0; rt < 2; ++rt)
#pragma unroll
        for (int ct = 0; ct < 7; ++ct)
            acc[rt][ct] = f32x4{0.f, 0.f, 0.f, 0.f};

    for (long base = (long)blockIdx.x * 64; base < R; base += (long)gridDim.x * 64) {
        __syncthreads();
        for (int idx = tid; idx < 50 * 64; idx += 256) {
            int r = idx / 50, c2 = (idx - r * 50) * 2;
            bf16x2 v2 = bf16x2{(bf16)0.f, (bf16)0.f};
            bf16x2 z2 = bf16x2{(bf16)0.f, (bf16)0.f};
            if (base + r < R) {
                v2 = *(const bf16x2*)(t + (base + r) * ld + 100 + c2);
                z2 = *(const bf16x2*)(t + (base + r) * ld + 200 + c2);
            }
            Vt[c2 * 72 + r] = v2[0]; Vt[(c2 + 1) * 72 + r] = v2[1];
            Zt[c2 * 72 + r] = z2[0]; Zt[(c2 + 1) * 72 + r] = z2[1];
        }
        __syncthreads();
#pragma unroll
        for (int ks = 0; ks < 2; ++ks) {
            int k0 = ks * 32 + quad * 8;
            bf16x8 b[7];
#pragma unroll
            for (int ct = 0; ct < 7; ++ct)
                b[ct] = *(const bf16x8*)&Zt[(ct * 16 + m) * 72 + k0];
#pragma unroll
            for (int rt = 0; rt < 2; ++rt) {
                int tr = wid + rt * 4;
                if (tr >= 7) continue;
                bf16x8 a = *(const bf16x8*)&Vt[(tr * 16 + m) * 72 + k0];
#pragma unroll
                for (int ct = 0; ct < 7; ++ct)
                    acc[rt][ct] = __builtin_amdgcn_mfma_f32_16x16x32_bf16(a, b[ct], acc[rt][ct], 0, 0, 0);
            }
        }
    }

    float* out = Mpart + (long)blockIdx.x * 10000;
#pragma unroll
    for (int rt = 0; rt < 2; ++rt) {
        int tr = wid + rt * 4;
        if (tr >= 7) continue;
#pragma unroll
        for (int ct = 0; ct < 7; ++ct) {
            int b = ct * 16 + m;
            if (b >= 100) continue;
#pragma unroll
            for (int r = 0; r < 4; ++r) {
                int a = tr * 16 + quad * 4 + r;
                if (a < 100) out[a * 100 + b] = acc[rt][ct][r];
            }
        }
    }
}

__global__ void vtz_reduce(const float* __restrict__ Mpart, float* __restrict__ M)
{
    int idx = blockIdx.x * 256 + threadIdx.x;
    if (idx >= 10000) return;
    float s = 0.f;
    for (int b = 0; b < VTZ_BLOCKS; ++b) s += Mpart[(long)b * 10000 + idx];
    M[idx] = s;
}

// ---------------- batch norm (y fp32)
__global__ void bn_stats(const float* __restrict__ y, int R, float* __restrict__ sums)
{
    int c = threadIdx.x;
    int i0 = blockIdx.x * 256;
    int i1 = i0 + 256; if (i1 > R) i1 = R;
    float s = 0.f, s2 = 0.f;
    for (int i = i0; i < i1; ++i) {
        float v = y[(long)i * 256 + c];
        s += v; s2 += v * v;
    }
    atomicAdd(&sums[c], s);
    atomicAdd(&sums[256 + c], s2);
}

__global__ void bn_finalize(const float* __restrict__ sums, const float* __restrict__ g,
                            const float* __restrict__ bt, int R, float* __restrict__ ab)
{
    int c = threadIdx.x;
    float mean = sums[c] / (float)R;
    float var  = sums[256 + c] / (float)R - mean * mean;
    if (var < 0.f) var = 0.f;
    float a = g[c] * rsqrtf(var + 1e-5f);
    ab[c] = a;
    ab[256 + c] = bt[c] - mean * a;
}

__global__ void bn_apply(const float* __restrict__ y, const float* __restrict__ ab,
                         int total, bf16* __restrict__ x)
{
    int idx = blockIdx.x * 256 + threadIdx.x;
    if (idx < total) {
        int c = idx & 255;
        x[idx] = (bf16)(y[idx] * ab[c] + ab[256 + c]);
    }
}

// =====================================================================================
extern "C" void kernel_launch(void* const* d_in, const int* in_sizes, int n_in,
                              void* d_out, int out_size, void* d_ws, size_t ws_size,
                              hipStream_t stream)
{
    (void)n_in; (void)out_size; (void)ws_size;
    const int N = in_sizes[0] / 128;       // 50000
    const int E = in_sizes[1] / 2;         // 800000

    const float* x0 = (const float*)d_in[0];
    const int*  ei   = (const int*)d_in[1];
    const int*  esrc = ei;
    const int*  edst = ei + E;
    const float *cw[3], *cbv[3], *aw[3], *abv[3], *rw[3], *rbv[3];
    for (int l = 0; l < 3; ++l) {
        cw[l]  = (const float*)d_in[2 + 6 * l];
        cbv[l] = (const float*)d_in[3 + 6 * l];
        aw[l]  = (const float*)d_in[4 + 6 * l];
        abv[l] = (const float*)d_in[5 + 6 * l];
        rw[l]  = (const float*)d_in[6 + 6 * l];
        rbv[l] = (const float*)d_in[7 + 6 * l];
    }
    const float* g[2]   = {(const float*)d_in[20], (const float*)d_in[22]};
    const float* btb[2] = {(const float*)d_in[21], (const float*)d_in[23]};

    // ---- workspace carve (~163 MB, below proven-good 166.5 MB) ----
    char* p = (char*)d_ws;
    auto carve = [&](size_t bytes) -> char* {
        char* r = p; p += (bytes + 255) & ~(size_t)255; return r;
    };
    int*   cnt    = (int*)carve((size_t)N * 4);
    int*   rowptr = (int*)carve((size_t)(N + 1) * 4);
    int*   cursor = (int*)carve((size_t)N * 4);
    int*   colidx = (int*)carve((size_t)E * 4);
    float* dis    = (float*)carve((size_t)N * 4);
    int*   csum   = (int*)carve(256 * 4);
    float* Mbuf   = (float*)carve(100 * 100 * 4);
    float* Mpart  = (float*)carve((size_t)VTZ_BLOCKS * 10000 * 4);
    float* csbuf  = (float*)carve(200 * 4);
    float* scale  = (float*)carve(256);
    float* bnsum  = (float*)carve(512 * 4);
    float* bnab   = (float*)carve(512 * 4);
    bf16*  MT     = (bf16*)carve(128 * 128 * 2);
    bf16*  cwT[3], *awT[3], *rwT[3];
    int din[3] = {128, 256, 256};
    int dou[3] = {256, 256, 128};
    for (int l = 0; l < 3; ++l) {
        cwT[l] = (bf16*)carve((size_t)256 * din[l] * 2);
        awT[l] = (bf16*)carve((size_t)512 * din[l] * 2);
        rwT[l] = (bf16*)carve((size_t)dou[l] * 480 * 2);
    }
    bf16*  xbf  = (bf16*)carve((size_t)N * 256 * 2);        // current x (bf16)
    float* hbuf = (float*)carve((size_t)N * 256 * 4);       // y (fp32); hb (bf16 h) aliases it
    bf16*  hb   = (bf16*)hbuf;                              // h bf16 — dead before y written
    bf16*  tbuf = (bf16*)carve((size_t)N * 300 * 2);        // U|V|Z (ld=300)
    bf16*  xcat = (bf16*)carve(((size_t)N * 456 + 32) * 2); // [res|T|xloc], ld=456

    // ---- CSR build (parallel scan) ----
    const int nchunks = (N + 1023) / 1024;
    hipMemsetAsync(cnt, 0, (size_t)N * 4, stream);
    hist_kernel<<<(E + 255) / 256, 256, 0, stream>>>(edst, E, cnt);
    scanA_kernel<<<nchunks, 1024, 0, stream>>>(cnt, N, csum);
    scanB_kernel<<<1, 64, 0, stream>>>(csum, nchunks, N, rowptr);
    scanC_kernel<<<nchunks, 1024, 0, stream>>>(cnt, N, csum, rowptr, cursor, dis);
    scatter_kernel<<<(E + 255) / 256, 256, 0, stream>>>(esrc, edst, E, cursor, colidx);

    // ---- weight transposes + x0 cast ----
    for (int l = 0; l < 3; ++l) {
        transpose_f2b<<<((long)256 * din[l] + 255) / 256, 256, 0, stream>>>(
            cw[l], din[l], 256, cwT[l], din[l], 256);
        transpose_f2b<<<((long)512 * din[l] + 255) / 256, 256, 0, stream>>>(
            aw[l], din[l], 400, awT[l], din[l], 512);
        transpose_f2b<<<((long)dou[l] * 480 + 255) / 256, 256, 0, stream>>>(
            rw[l], 456, dou[l], rwT[l], 480, dou[l]);
    }
    cast_f2b<<<((long)N * 128 + 255) / 256, 256, 0, stream>>>(x0, (long)N * 128, xbf);

    int lda = 128;
    const unsigned gx = (unsigned)((N + 127) / 128);

    for (int l = 0; l < 3; ++l) {
        // 1) h = x @ cw -> hb (bf16; bias/relu deferred to agg)
        gemm_mfma<<<dim3(gx, 2), 256, 0, stream>>>(xbf, lda, cwT[l], din[l], nullptr,
                                                   hb, nullptr, 256, N, 256, 0, nullptr);
        // 2) U|V|Z = relu(x @ aw[:,0:300] + ab[0:300]) -> tbuf
        gemm_mfma<<<dim3(gx, 3), 256, 0, stream>>>(xbf, lda, awT[l], din[l], abv[l],
                                                   tbuf, nullptr, 300, N, 300, 1, nullptr);
        // 3) T = relu(x @ aw[:,300:400] + ab[300:]) -> xcat cols 100..199
        gemm_mfma<<<dim3(gx, 1), 256, 0, stream>>>(xbf, lda, awT[l] + (long)300 * din[l], din[l],
                                                   abv[l] + 300,
                                                   xcat + 100, nullptr, 456, N, 100, 1, nullptr);
        // 4) colsums + nf
        hipMemsetAsync(csbuf, 0, 200 * 4, stream);
        colsum_kernel<<<(N + 255) / 256, 256, 0, stream>>>(tbuf, 300, N, csbuf);
        nf_kernel<<<1, 128, 0, stream>>>(csbuf, scale, N);
        // 5) M = V^T Z (MFMA two-stage) ; transpose/cast to MT
        vtz_mfma<<<VTZ_BLOCKS, 256, 0, stream>>>(tbuf, 300, N, Mpart);
        vtz_reduce<<<40, 256, 0, stream>>>(Mpart, Mbuf);
        transpose_M<<<64, 256, 0, stream>>>(Mbuf, MT);
        // 6) res = scale * (U @ M) -> xcat cols 0..99
        gemm_mfma<<<dim3(gx, 1), 256, 0, stream>>>(tbuf, 300, MT, 128, nullptr,
                                                   xcat, nullptr, 456, N, 100, 0, scale);
        // 7) x_local = relu(agg + cb) -> xcat cols 200..455
        agg_kernel<<<(N + 3) / 4, 256, 0, stream>>>(hb, rowptr, colidx, dis, cbv[l],
                                                    xcat + 200, 456, N);
        // 8) readout (Kd=480: cols 456..479 junk x zero weight rows = 0)
        if (l < 2) {
            gemm_mfma<<<dim3(gx, 2), 256, 0, stream>>>(xcat, 456, rwT[l], 480, rbv[l],
                                                       nullptr, hbuf, 256, N, 256, 1, nullptr);
            hipMemsetAsync(bnsum, 0, 512 * 4, stream);
            bn_stats<<<(N + 255) / 256, 256, 0, stream>>>(hbuf, N, bnsum);
            bn_finalize<<<1, 256, 0, stream>>>(bnsum, g[l], btb[l], N, bnab);
            bn_apply<<<((long)N * 256 + 255) / 256, 256, 0, stream>>>(hbuf, bnab, N * 256, xbf);
            lda = 256;
        } else {
            gemm_mfma<<<dim3(gx, 1), 256, 0, stream>>>(xcat, 456, rwT[l], 480, rbv[l],
                                                       nullptr, (float*)d_out, 128, N, 128, 0, nullptr);
        }
    }
}

// Round 10
// 1208.226 us; speedup vs baseline: 1.5368x; 1.2004x over previous
//
#include <hip/hip_runtime.h>

typedef __bf16 bf16;
typedef __attribute__((ext_vector_type(8))) __bf16 bf16x8;
typedef __attribute__((ext_vector_type(4))) __bf16 bf16x4;
typedef __attribute__((ext_vector_type(2))) __bf16 bf16x2;
typedef __attribute__((ext_vector_type(4))) float f32x4;

// ---------------- narrow MFMA GEMM: 128x128 block tile, register-prefetched K-loop.
// Next iteration's A/B global loads issue right after the LDS-ready barrier and are
// consumed at the next LDS store — global latency overlaps MFMA + LDS reads.
__global__ __launch_bounds__(256) void gemm_mfma(
    const bf16* __restrict__ A, int lda,
    const bf16* __restrict__ Bt, int Kd,
    const float* __restrict__ bias,
    bf16* __restrict__ Cb, float* __restrict__ Cf, int ldc,
    int R, int ncols, int relu,
    const float* __restrict__ scale_ptr)
{
    __shared__ bf16 Bs[128 * 40];
    const int tid  = threadIdx.x;
    const int wid  = tid >> 6;
    const int lane = tid & 63;
    const int m    = lane & 15;
    const int quad = lane >> 4;

    const long row0    = (long)blockIdx.x * 128 + wid * 32;
    const int  colbase = blockIdx.y * 128;

    f32x4 acc[2][8];
#pragma unroll
    for (int rt = 0; rt < 2; ++rt)
#pragma unroll
        for (int ct = 0; ct < 8; ++ct)
            acc[rt][ct] = f32x4{0.f, 0.f, 0.f, 0.f};

    const bf16* Aptr[2];
#pragma unroll
    for (int rt = 0; rt < 2; ++rt) {
        long r = row0 + rt * 16 + m;
        if (r > (long)R - 1) r = (long)R - 1;
        Aptr[rt] = A + r * (long)lda + quad * 8;
    }
    const bf16* Bstage = Bt + ((long)colbase + (tid >> 2)) * Kd + (tid & 3) * 8;
    const int   skk    = (tid & 3) * 8;
    const int   sc     = tid >> 2;

    // prologue: prefetch k=0
    bf16x8 pa0 = *(const bf16x8*)(Aptr[0]);
    bf16x8 pa1 = *(const bf16x8*)(Aptr[1]);
    bf16x8 pb0 = *(const bf16x8*)(Bstage);
    bf16x8 pb1 = *(const bf16x8*)(Bstage + (long)64 * Kd);

    for (int k = 0; k < Kd; k += 32) {
        __syncthreads();
        *(bf16x8*)&Bs[sc * 40 + skk]        = pb0;
        *(bf16x8*)&Bs[(sc + 64) * 40 + skk] = pb1;
        __syncthreads();
        bf16x8 a0 = pa0, a1 = pa1;
        if (k + 32 < Kd) {           // prefetch next iteration (overlaps MFMA below)
            pb0 = *(const bf16x8*)(Bstage + k + 32);
            pb1 = *(const bf16x8*)(Bstage + (long)64 * Kd + k + 32);
            pa0 = *(const bf16x8*)(Aptr[0] + k + 32);
            pa1 = *(const bf16x8*)(Aptr[1] + k + 32);
        }
#pragma unroll
        for (int ct = 0; ct < 8; ++ct) {
            bf16x8 b = *(const bf16x8*)&Bs[(ct * 16 + m) * 40 + quad * 8];
            acc[0][ct] = __builtin_amdgcn_mfma_f32_16x16x32_bf16(a0, b, acc[0][ct], 0, 0, 0);
            acc[1][ct] = __builtin_amdgcn_mfma_f32_16x16x32_bf16(a1, b, acc[1][ct], 0, 0, 0);
        }
    }

    const float scale = scale_ptr ? *scale_ptr : 1.f;
#pragma unroll
    for (int ct = 0; ct < 8; ++ct) {
        int col = colbase + ct * 16 + m;
        if (col >= ncols) continue;
        float bv = bias ? bias[col] : 0.f;
#pragma unroll
        for (int rt = 0; rt < 2; ++rt) {
#pragma unroll
            for (int r = 0; r < 4; ++r) {
                long row = row0 + rt * 16 + quad * 4 + r;
                if (row < R) {
                    float v = acc[rt][ct][r] * scale + bv;
                    if (relu && v < 0.f) v = 0.f;
                    if (Cf) Cf[row * (long)ldc + col] = v;
                    else    Cb[row * (long)ldc + col] = (bf16)v;
                }
            }
        }
    }
}

// ---------------- weight transpose + cast
__global__ void transpose_f2b(const float* __restrict__ in, int K, int ncols,
                              bf16* __restrict__ out, int Kd, int npad)
{
    long idx = (long)blockIdx.x * 256 + threadIdx.x;
    long total = (long)npad * Kd;
    if (idx >= total) return;
    int k = (int)(idx % Kd);
    int n = (int)(idx / Kd);
    float v = (k < K && n < ncols) ? in[(long)k * ncols + n] : 0.f;
    out[idx] = (bf16)v;
}

__global__ void transpose_M(const float* __restrict__ M, bf16* __restrict__ out)
{
    int idx = blockIdx.x * 256 + threadIdx.x;
    int k = idx & 127, n = idx >> 7;
    float v = (k < 100 && n < 100) ? M[k * 100 + n] : 0.f;
    out[idx] = (bf16)v;
}

__global__ void cast_f2b(const float* __restrict__ in, long total, bf16* __restrict__ out)
{
    long idx = (long)blockIdx.x * 256 + threadIdx.x;
    if (idx < total) out[idx] = (bf16)in[idx];
}

// ---------------- CSR build: hist + 3-phase parallel scan + scatter
__global__ void hist_kernel(const int* __restrict__ dst, int E, int* __restrict__ cnt)
{
    int e = blockIdx.x * 256 + threadIdx.x;
    if (e < E) atomicAdd(&cnt[dst[e]], 1);
}

__global__ __launch_bounds__(1024) void scanA_kernel(const int* __restrict__ cnt, int n,
                                                     int* __restrict__ csum)
{
    __shared__ int sdata[1024];
    int t = threadIdx.x;
    int i = blockIdx.x * 1024 + t;
    sdata[t] = (i < n) ? cnt[i] : 0;
    __syncthreads();
    for (int d = 512; d > 0; d >>= 1) {
        if (t < d) sdata[t] += sdata[t + d];
        __syncthreads();
    }
    if (t == 0) csum[blockIdx.x] = sdata[0];
}

__global__ void scanB_kernel(int* __restrict__ csum, int nchunks, int n, int* __restrict__ rowptr)
{
    if (threadIdx.x == 0) {
        int run = 0;
        for (int b = 0; b < nchunks; ++b) {
            int v = csum[b];
            csum[b] = run;
            run += v;
        }
        rowptr[n] = run;
    }
}

__global__ __launch_bounds__(1024) void scanC_kernel(const int* __restrict__ cnt, int n,
                                                     const int* __restrict__ csum,
                                                     int* __restrict__ rowptr,
                                                     int* __restrict__ cursor,
                                                     float* __restrict__ dis)
{
    __shared__ int sdata[1024];
    int t = threadIdx.x;
    int i = blockIdx.x * 1024 + t;
    int v = (i < n) ? cnt[i] : 0;
    sdata[t] = v;
    __syncthreads();
    for (int d = 1; d < 1024; d <<= 1) {
        int x = (t >= d) ? sdata[t - d] : 0;
        __syncthreads();
        sdata[t] += x;
        __syncthreads();
    }
    if (i < n) {
        int excl = csum[blockIdx.x] + sdata[t] - v;
        rowptr[i] = excl;
        cursor[i] = excl;
        dis[i] = rsqrtf((float)(v + 1));   // deg = in-degree + self-loop
    }
}

__global__ void scatter_kernel(const int* __restrict__ src, const int* __restrict__ dst,
                               int E, int* __restrict__ cursor, int* __restrict__ colidx)
{
    int e = blockIdx.x * 256 + threadIdx.x;
    if (e < E) {
        int d = dst[e];
        int pos = atomicAdd(&cursor[d], 1);
        colidx[pos] = src[e];
    }
}

// ---------------- GCN aggregation: one wave per dst node, bf16 h, 4x edge unroll
__global__ __launch_bounds__(256) void agg_kernel(
    const bf16* __restrict__ h, const int* __restrict__ rowptr,
    const int* __restrict__ colidx, const float* __restrict__ dis,
    const float* __restrict__ cb, bf16* __restrict__ out, int ldc, int R)
{
    int wid = threadIdx.x >> 6, lane = threadIdx.x & 63;
    int i = blockIdx.x * 4 + wid;
    if (i >= R) return;
    float disi = dis[i];
    bf16x4 hv = *(const bf16x4*)(h + (long)i * 256 + lane * 4);
    float acc[4];
#pragma unroll
    for (int j = 0; j < 4; ++j) acc[j] = (float)hv[j] * disi;  // self loop
    int e0 = rowptr[i], e1 = rowptr[i + 1];
    int e = e0;
    for (; e + 3 < e1; e += 4) {
        int s0 = colidx[e], s1 = colidx[e + 1], s2 = colidx[e + 2], s3 = colidx[e + 3];
        float w0 = dis[s0], w1 = dis[s1], w2 = dis[s2], w3 = dis[s3];
        bf16x4 h0 = *(const bf16x4*)(h + (long)s0 * 256 + lane * 4);
        bf16x4 h1 = *(const bf16x4*)(h + (long)s1 * 256 + lane * 4);
        bf16x4 h2 = *(const bf16x4*)(h + (long)s2 * 256 + lane * 4);
        bf16x4 h3 = *(const bf16x4*)(h + (long)s3 * 256 + lane * 4);
#pragma unroll
        for (int j = 0; j < 4; ++j)
            acc[j] += (float)h0[j] * w0 + (float)h1[j] * w1
                    + (float)h2[j] * w2 + (float)h3[j] * w3;
    }
    for (; e < e1; ++e) {
        int s = colidx[e];
        float w = dis[s];
        bf16x4 hs = *(const bf16x4*)(h + (long)s * 256 + lane * 4);
#pragma unroll
        for (int j = 0; j < 4; ++j) acc[j] += (float)hs[j] * w;
    }
    bf16x4 o;
#pragma unroll
    for (int j = 0; j < 4; ++j) {
        float v = acc[j] * disi + cb[lane * 4 + j];
        if (v < 0.f) v = 0.f;
        o[j] = (bf16)v;
    }
    *(bf16x4*)(out + (long)i * ldc + lane * 4) = o;
}

// ---------------- column sums of U,V — 64 rows/block, 4x unroll (latency-hiding)
__global__ void colsum_kernel(const bf16* __restrict__ t, int ld, int R, float* __restrict__ cs)
{
    int c = threadIdx.x;
    if (c >= 200) return;
    int i0 = blockIdx.x * 64;
    int i1 = i0 + 64; if (i1 > R) i1 = R;
    float s = 0.f;
    int i = i0;
    for (; i + 3 < i1; i += 4) {
        float v0 = (float)t[(long)i * ld + c];
        float v1 = (float)t[(long)(i + 1) * ld + c];
        float v2 = (float)t[(long)(i + 2) * ld + c];
        float v3 = (float)t[(long)(i + 3) * ld + c];
        s += (v0 + v1) + (v2 + v3);
    }
    for (; i < i1; ++i) s += (float)t[(long)i * ld + c];
    atomicAdd(&cs[c], s);
}

__global__ void nf_kernel(const float* __restrict__ cs, float* __restrict__ scale, int R)
{
    __shared__ float s[128];
    int t = threadIdx.x;
    float v = (t < 100) ? cs[t] * cs[100 + t] : 0.f;
    s[t] = v;
    __syncthreads();
    for (int d = 64; d > 0; d >>= 1) {
        if (t < d) s[t] += s[t + d];
        __syncthreads();
    }
    if (t == 0) scale[0] = 1.0f / (s[0] / (float)R + 1e-6f);
}

// ---------------- M = V^T Z via MFMA, two-stage, no atomics
#define VTZ_BLOCKS 128
__global__ __launch_bounds__(256) void vtz_mfma(const bf16* __restrict__ t, int ld, int R,
                                                float* __restrict__ Mpart)
{
    __shared__ bf16 Vt[112 * 72];
    __shared__ bf16 Zt[112 * 72];
    const int tid  = threadIdx.x;
    const int wid  = tid >> 6;
    const int lane = tid & 63;
    const int m    = lane & 15;
    const int quad = lane >> 4;

    for (int idx = tid; idx < 12 * 64; idx += 256) {
        int c = 100 + (idx >> 6), r = idx & 63;
        Vt[c * 72 + r] = (bf16)0.f;
        Zt[c * 72 + r] = (bf16)0.f;
    }

    f32x4 acc[2][7];
#pragma unroll
    for (int rt = 0; rt < 2; ++rt)
#pragma unroll
        for (int ct = 0; ct < 7; ++ct)
            acc[rt][ct] = f32x4{0.f, 0.f, 0.f, 0.f};

    for (long base = (long)blockIdx.x * 64; base < R; base += (long)gridDim.x * 64) {
        __syncthreads();
        for (int idx = tid; idx < 50 * 64; idx += 256) {
            int r = idx / 50, c2 = (idx - r * 50) * 2;
            bf16x2 v2 = bf16x2{(bf16)0.f, (bf16)0.f};
            bf16x2 z2 = bf16x2{(bf16)0.f, (bf16)0.f};
            if (base + r < R) {
                v2 = *(const bf16x2*)(t + (base + r) * ld + 100 + c2);
                z2 = *(const bf16x2*)(t + (base + r) * ld + 200 + c2);
            }
            Vt[c2 * 72 + r] = v2[0]; Vt[(c2 + 1) * 72 + r] = v2[1];
            Zt[c2 * 72 + r] = z2[0]; Zt[(c2 + 1) * 72 + r] = z2[1];
        }
        __syncthreads();
#pragma unroll
        for (int ks = 0; ks < 2; ++ks) {
            int k0 = ks * 32 + quad * 8;
            bf16x8 b[7];
#pragma unroll
            for (int ct = 0; ct < 7; ++ct)
                b[ct] = *(const bf16x8*)&Zt[(ct * 16 + m) * 72 + k0];
#pragma unroll
            for (int rt = 0; rt < 2; ++rt) {
                int tr = wid + rt * 4;
                if (tr >= 7) continue;
                bf16x8 a = *(const bf16x8*)&Vt[(tr * 16 + m) * 72 + k0];
#pragma unroll
                for (int ct = 0; ct < 7; ++ct)
                    acc[rt][ct] = __builtin_amdgcn_mfma_f32_16x16x32_bf16(a, b[ct], acc[rt][ct], 0, 0, 0);
            }
        }
    }

    float* out = Mpart + (long)blockIdx.x * 10000;
#pragma unroll
    for (int rt = 0; rt < 2; ++rt) {
        int tr = wid + rt * 4;
        if (tr >= 7) continue;
#pragma unroll
        for (int ct = 0; ct < 7; ++ct) {
            int b = ct * 16 + m;
            if (b >= 100) continue;
#pragma unroll
            for (int r = 0; r < 4; ++r) {
                int a = tr * 16 + quad * 4 + r;
                if (a < 100) out[a * 100 + b] = acc[rt][ct][r];
            }
        }
    }
}

__global__ void vtz_reduce(const float* __restrict__ Mpart, float* __restrict__ M)
{
    int idx = blockIdx.x * 256 + threadIdx.x;
    if (idx >= 10000) return;
    float s = 0.f;
    for (int b = 0; b < VTZ_BLOCKS; ++b) s += Mpart[(long)b * 10000 + idx];
    M[idx] = s;
}

// ---------------- batch norm (y fp32) — 64 rows/block, 4x unroll (latency-hiding)
__global__ void bn_stats(const float* __restrict__ y, int R, float* __restrict__ sums)
{
    int c = threadIdx.x;
    int i0 = blockIdx.x * 64;
    int i1 = i0 + 64; if (i1 > R) i1 = R;
    float s = 0.f, s2 = 0.f;
    int i = i0;
    for (; i + 3 < i1; i += 4) {
        float v0 = y[(long)i * 256 + c];
        float v1 = y[(long)(i + 1) * 256 + c];
        float v2 = y[(long)(i + 2) * 256 + c];
        float v3 = y[(long)(i + 3) * 256 + c];
        s  += (v0 + v1) + (v2 + v3);
        s2 += (v0 * v0 + v1 * v1) + (v2 * v2 + v3 * v3);
    }
    for (; i < i1; ++i) {
        float v = y[(long)i * 256 + c];
        s += v; s2 += v * v;
    }
    atomicAdd(&sums[c], s);
    atomicAdd(&sums[256 + c], s2);
}

__global__ void bn_finalize(const float* __restrict__ sums, const float* __restrict__ g,
                            const float* __restrict__ bt, int R, float* __restrict__ ab)
{
    int c = threadIdx.x;
    float mean = sums[c] / (float)R;
    float var  = sums[256 + c] / (float)R - mean * mean;
    if (var < 0.f) var = 0.f;
    float a = g[c] * rsqrtf(var + 1e-5f);
    ab[c] = a;
    ab[256 + c] = bt[c] - mean * a;
}

__global__ void bn_apply(const float* __restrict__ y, const float* __restrict__ ab,
                         int total, bf16* __restrict__ x)
{
    int idx = blockIdx.x * 256 + threadIdx.x;
    if (idx < total) {
        int c = idx & 255;
        x[idx] = (bf16)(y[idx] * ab[c] + ab[256 + c]);
    }
}

// =====================================================================================
extern "C" void kernel_launch(void* const* d_in, const int* in_sizes, int n_in,
                              void* d_out, int out_size, void* d_ws, size_t ws_size,
                              hipStream_t stream)
{
    (void)n_in; (void)out_size; (void)ws_size;
    const int N = in_sizes[0] / 128;       // 50000
    const int E = in_sizes[1] / 2;         // 800000

    const float* x0 = (const float*)d_in[0];
    const int*  ei   = (const int*)d_in[1];
    const int*  esrc = ei;
    const int*  edst = ei + E;
    const float *cw[3], *cbv[3], *aw[3], *abv[3], *rw[3], *rbv[3];
    for (int l = 0; l < 3; ++l) {
        cw[l]  = (const float*)d_in[2 + 6 * l];
        cbv[l] = (const float*)d_in[3 + 6 * l];
        aw[l]  = (const float*)d_in[4 + 6 * l];
        abv[l] = (const float*)d_in[5 + 6 * l];
        rw[l]  = (const float*)d_in[6 + 6 * l];
        rbv[l] = (const float*)d_in[7 + 6 * l];
    }
    const float* g[2]   = {(const float*)d_in[20], (const float*)d_in[22]};
    const float* btb[2] = {(const float*)d_in[21], (const float*)d_in[23]};

    // ---- workspace carve (~163 MB, below proven-good 166.5 MB) ----
    char* p = (char*)d_ws;
    auto carve = [&](size_t bytes) -> char* {
        char* r = p; p += (bytes + 255) & ~(size_t)255; return r;
    };
    int*   cnt    = (int*)carve((size_t)N * 4);
    int*   rowptr = (int*)carve((size_t)(N + 1) * 4);
    int*   cursor = (int*)carve((size_t)N * 4);
    int*   colidx = (int*)carve((size_t)E * 4);
    float* dis    = (float*)carve((size_t)N * 4);
    int*   csum   = (int*)carve(256 * 4);
    float* Mbuf   = (float*)carve(100 * 100 * 4);
    float* Mpart  = (float*)carve((size_t)VTZ_BLOCKS * 10000 * 4);
    float* csbuf  = (float*)carve(200 * 4);
    float* scale  = (float*)carve(256);
    float* bnsum  = (float*)carve(512 * 4);
    float* bnab   = (float*)carve(512 * 4);
    bf16*  MT     = (bf16*)carve(128 * 128 * 2);
    bf16*  cwT[3], *awT[3], *rwT[3];
    int din[3] = {128, 256, 256};
    int dou[3] = {256, 256, 128};
    for (int l = 0; l < 3; ++l) {
        cwT[l] = (bf16*)carve((size_t)256 * din[l] * 2);
        awT[l] = (bf16*)carve((size_t)512 * din[l] * 2);
        rwT[l] = (bf16*)carve((size_t)dou[l] * 480 * 2);
    }
    bf16*  xbf  = (bf16*)carve((size_t)N * 256 * 2);        // current x (bf16)
    float* hbuf = (float*)carve((size_t)N * 256 * 4);       // y (fp32); hb (bf16 h) aliases it
    bf16*  hb   = (bf16*)hbuf;                              // h bf16 — dead before y written
    bf16*  tbuf = (bf16*)carve((size_t)N * 300 * 2);        // U|V|Z (ld=300)
    bf16*  xcat = (bf16*)carve(((size_t)N * 456 + 32) * 2); // [res|T|xloc], ld=456

    // ---- CSR build (parallel scan) ----
    const int nchunks = (N + 1023) / 1024;
    hipMemsetAsync(cnt, 0, (size_t)N * 4, stream);
    hist_kernel<<<(E + 255) / 256, 256, 0, stream>>>(edst, E, cnt);
    scanA_kernel<<<nchunks, 1024, 0, stream>>>(cnt, N, csum);
    scanB_kernel<<<1, 64, 0, stream>>>(csum, nchunks, N, rowptr);
    scanC_kernel<<<nchunks, 1024, 0, stream>>>(cnt, N, csum, rowptr, cursor, dis);
    scatter_kernel<<<(E + 255) / 256, 256, 0, stream>>>(esrc, edst, E, cursor, colidx);

    // ---- weight transposes + x0 cast ----
    for (int l = 0; l < 3; ++l) {
        transpose_f2b<<<((long)256 * din[l] + 255) / 256, 256, 0, stream>>>(
            cw[l], din[l], 256, cwT[l], din[l], 256);
        transpose_f2b<<<((long)512 * din[l] + 255) / 256, 256, 0, stream>>>(
            aw[l], din[l], 400, awT[l], din[l], 512);
        transpose_f2b<<<((long)dou[l] * 480 + 255) / 256, 256, 0, stream>>>(
            rw[l], 456, dou[l], rwT[l], 480, dou[l]);
    }
    cast_f2b<<<((long)N * 128 + 255) / 256, 256, 0, stream>>>(x0, (long)N * 128, xbf);

    int lda = 128;
    const unsigned gx = (unsigned)((N + 127) / 128);
    const unsigned gr = (unsigned)((N + 63) / 64);   // 64-row blocks for stats/colsum

    for (int l = 0; l < 3; ++l) {
        // 1) h = x @ cw -> hb (bf16; bias/relu deferred to agg)
        gemm_mfma<<<dim3(gx, 2), 256, 0, stream>>>(xbf, lda, cwT[l], din[l], nullptr,
                                                   hb, nullptr, 256, N, 256, 0, nullptr);
        // 2) U|V|Z = relu(x @ aw[:,0:300] + ab[0:300]) -> tbuf
        gemm_mfma<<<dim3(gx, 3), 256, 0, stream>>>(xbf, lda, awT[l], din[l], abv[l],
                                                   tbuf, nullptr, 300, N, 300, 1, nullptr);
        // 3) T = relu(x @ aw[:,300:400] + ab[300:]) -> xcat cols 100..199
        gemm_mfma<<<dim3(gx, 1), 256, 0, stream>>>(xbf, lda, awT[l] + (long)300 * din[l], din[l],
                                                   abv[l] + 300,
                                                   xcat + 100, nullptr, 456, N, 100, 1, nullptr);
        // 4) colsums + nf
        hipMemsetAsync(csbuf, 0, 200 * 4, stream);
        colsum_kernel<<<gr, 256, 0, stream>>>(tbuf, 300, N, csbuf);
        nf_kernel<<<1, 128, 0, stream>>>(csbuf, scale, N);
        // 5) M = V^T Z (MFMA two-stage) ; transpose/cast to MT
        vtz_mfma<<<VTZ_BLOCKS, 256, 0, stream>>>(tbuf, 300, N, Mpart);
        vtz_reduce<<<40, 256, 0, stream>>>(Mpart, Mbuf);
        transpose_M<<<64, 256, 0, stream>>>(Mbuf, MT);
        // 6) res = scale * (U @ M) -> xcat cols 0..99
        gemm_mfma<<<dim3(gx, 1), 256, 0, stream>>>(tbuf, 300, MT, 128, nullptr,
                                                   xcat, nullptr, 456, N, 100, 0, scale);
        // 7) x_local = relu(agg + cb) -> xcat cols 200..455
        agg_kernel<<<(N + 3) / 4, 256, 0, stream>>>(hb, rowptr, colidx, dis, cbv[l],
                                                    xcat + 200, 456, N);
        // 8) readout (Kd=480: cols 456..479 junk x zero weight rows = 0)
        if (l < 2) {
            gemm_mfma<<<dim3(gx, 2), 256, 0, stream>>>(xcat, 456, rwT[l], 480, rbv[l],
                                                       nullptr, hbuf, 256, N, 256, 1, nullptr);
            hipMemsetAsync(bnsum, 0, 512 * 4, stream);
            bn_stats<<<gr, 256, 0, stream>>>(hbuf, N, bnsum);
            bn_finalize<<<1, 256, 0, stream>>>(bnsum, g[l], btb[l], N, bnab);
            bn_apply<<<((long)N * 256 + 255) / 256, 256, 0, stream>>>(hbuf, bnab, N * 256, xbf);
            lda = 256;
        } else {
            gemm_mfma<<<dim3(gx, 1), 256, 0, stream>>>(xcat, 456, rwT[l], 480, rbv[l],
                                                       nullptr, (float*)d_out, 128, N, 128, 0, nullptr);
        }
    }
}

// Round 11
// 1040.880 us; speedup vs baseline: 1.7839x; 1.1608x over previous
//
#include <hip/hip_runtime.h>

typedef __bf16 bf16;
typedef __attribute__((ext_vector_type(8))) __bf16 bf16x8;
typedef __attribute__((ext_vector_type(4))) __bf16 bf16x4;
typedef __attribute__((ext_vector_type(2))) __bf16 bf16x2;
typedef __attribute__((ext_vector_type(4))) float f32x4;

// ---------------- narrow MFMA GEMM: 128x128 tile, register-prefetched K-loop (ncols <= 128 paths)
__global__ __launch_bounds__(256) void gemm_mfma(
    const bf16* __restrict__ A, int lda,
    const bf16* __restrict__ Bt, int Kd,
    const float* __restrict__ bias,
    bf16* __restrict__ Cb, float* __restrict__ Cf, int ldc,
    int R, int ncols, int relu,
    const float* __restrict__ scale_ptr)
{
    __shared__ bf16 Bs[128 * 40];
    const int tid  = threadIdx.x;
    const int wid  = tid >> 6;
    const int lane = tid & 63;
    const int m    = lane & 15;
    const int quad = lane >> 4;

    const long row0    = (long)blockIdx.x * 128 + wid * 32;
    const int  colbase = blockIdx.y * 128;

    f32x4 acc[2][8];
#pragma unroll
    for (int rt = 0; rt < 2; ++rt)
#pragma unroll
        for (int ct = 0; ct < 8; ++ct)
            acc[rt][ct] = f32x4{0.f, 0.f, 0.f, 0.f};

    const bf16* Aptr[2];
#pragma unroll
    for (int rt = 0; rt < 2; ++rt) {
        long r = row0 + rt * 16 + m;
        if (r > (long)R - 1) r = (long)R - 1;
        Aptr[rt] = A + r * (long)lda + quad * 8;
    }
    const bf16* Bstage = Bt + ((long)colbase + (tid >> 2)) * Kd + (tid & 3) * 8;
    const int   skk    = (tid & 3) * 8;
    const int   sc     = tid >> 2;

    bf16x8 pa0 = *(const bf16x8*)(Aptr[0]);
    bf16x8 pa1 = *(const bf16x8*)(Aptr[1]);
    bf16x8 pb0 = *(const bf16x8*)(Bstage);
    bf16x8 pb1 = *(const bf16x8*)(Bstage + (long)64 * Kd);

    for (int k = 0; k < Kd; k += 32) {
        __syncthreads();
        *(bf16x8*)&Bs[sc * 40 + skk]        = pb0;
        *(bf16x8*)&Bs[(sc + 64) * 40 + skk] = pb1;
        __syncthreads();
        bf16x8 a0 = pa0, a1 = pa1;
        if (k + 32 < Kd) {
            pb0 = *(const bf16x8*)(Bstage + k + 32);
            pb1 = *(const bf16x8*)(Bstage + (long)64 * Kd + k + 32);
            pa0 = *(const bf16x8*)(Aptr[0] + k + 32);
            pa1 = *(const bf16x8*)(Aptr[1] + k + 32);
        }
#pragma unroll
        for (int ct = 0; ct < 8; ++ct) {
            bf16x8 b = *(const bf16x8*)&Bs[(ct * 16 + m) * 40 + quad * 8];
            acc[0][ct] = __builtin_amdgcn_mfma_f32_16x16x32_bf16(a0, b, acc[0][ct], 0, 0, 0);
            acc[1][ct] = __builtin_amdgcn_mfma_f32_16x16x32_bf16(a1, b, acc[1][ct], 0, 0, 0);
        }
    }

    const float scale = scale_ptr ? *scale_ptr : 1.f;
#pragma unroll
    for (int ct = 0; ct < 8; ++ct) {
        int col = colbase + ct * 16 + m;
        if (col >= ncols) continue;
        float bv = bias ? bias[col] : 0.f;
#pragma unroll
        for (int rt = 0; rt < 2; ++rt) {
#pragma unroll
            for (int r = 0; r < 4; ++r) {
                long row = row0 + rt * 16 + quad * 4 + r;
                if (row < R) {
                    float v = acc[rt][ct][r] * scale + bv;
                    if (relu && v < 0.f) v = 0.f;
                    if (Cf) Cf[row * (long)ldc + col] = v;
                    else    Cb[row * (long)ldc + col] = (bf16)v;
                }
            }
        }
    }
}

// ---------------- tall MFMA GEMM: 256x128 tile (4 waves x 64 rows), prefetched K-loop,
// optional fused column reductions: colsum (cols<200) and/or bn sum+sumsq.
__global__ __launch_bounds__(256, 2) void gemm_mfma_t(
    const bf16* __restrict__ A, int lda,
    const bf16* __restrict__ Bt, int Kd,
    const float* __restrict__ bias,
    bf16* __restrict__ Cb, float* __restrict__ Cf, int ldc,
    int R, int ncols, int relu,
    const float* __restrict__ scale_ptr,
    float* __restrict__ colsum_ptr,
    float* __restrict__ bnsum_ptr)
{
    __shared__ bf16 Bs[128 * 40];   // 10 KB; reused as float scratch in reduction epilogue
    const int tid  = threadIdx.x;
    const int wid  = tid >> 6;
    const int lane = tid & 63;
    const int m    = lane & 15;
    const int quad = lane >> 4;

    const long row0    = (long)blockIdx.x * 256 + wid * 64;
    const int  colbase = blockIdx.y * 128;

    f32x4 acc[4][8];
#pragma unroll
    for (int rt = 0; rt < 4; ++rt)
#pragma unroll
        for (int ct = 0; ct < 8; ++ct)
            acc[rt][ct] = f32x4{0.f, 0.f, 0.f, 0.f};

    const bf16* Aptr[4];
#pragma unroll
    for (int rt = 0; rt < 4; ++rt) {
        long r = row0 + rt * 16 + m;
        if (r > (long)R - 1) r = (long)R - 1;
        Aptr[rt] = A + r * (long)lda + quad * 8;
    }
    const bf16* Bstage = Bt + ((long)colbase + (tid >> 2)) * Kd + (tid & 3) * 8;
    const int   skk    = (tid & 3) * 8;
    const int   sc     = tid >> 2;

    bf16x8 pa[4], pb0, pb1;
#pragma unroll
    for (int rt = 0; rt < 4; ++rt) pa[rt] = *(const bf16x8*)(Aptr[rt]);
    pb0 = *(const bf16x8*)(Bstage);
    pb1 = *(const bf16x8*)(Bstage + (long)64 * Kd);

    for (int k = 0; k < Kd; k += 32) {
        __syncthreads();
        *(bf16x8*)&Bs[sc * 40 + skk]        = pb0;
        *(bf16x8*)&Bs[(sc + 64) * 40 + skk] = pb1;
        __syncthreads();
        bf16x8 a[4];
#pragma unroll
        for (int rt = 0; rt < 4; ++rt) a[rt] = pa[rt];
        if (k + 32 < Kd) {
            pb0 = *(const bf16x8*)(Bstage + k + 32);
            pb1 = *(const bf16x8*)(Bstage + (long)64 * Kd + k + 32);
#pragma unroll
            for (int rt = 0; rt < 4; ++rt) pa[rt] = *(const bf16x8*)(Aptr[rt] + k + 32);
        }
#pragma unroll
        for (int ct = 0; ct < 8; ++ct) {
            bf16x8 b = *(const bf16x8*)&Bs[(ct * 16 + m) * 40 + quad * 8];
#pragma unroll
            for (int rt = 0; rt < 4; ++rt)
                acc[rt][ct] = __builtin_amdgcn_mfma_f32_16x16x32_bf16(a[rt], b, acc[rt][ct], 0, 0, 0);
        }
    }

    const float scale = scale_ptr ? *scale_ptr : 1.f;
    float rsum[8], rsq[8];
#pragma unroll
    for (int ct = 0; ct < 8; ++ct) { rsum[ct] = 0.f; rsq[ct] = 0.f; }

#pragma unroll
    for (int ct = 0; ct < 8; ++ct) {
        int col = colbase + ct * 16 + m;
        if (col >= ncols) continue;
        float bv = bias ? bias[col] : 0.f;
#pragma unroll
        for (int rt = 0; rt < 4; ++rt) {
#pragma unroll
            for (int r = 0; r < 4; ++r) {
                long row = row0 + rt * 16 + quad * 4 + r;
                if (row < R) {
                    float v = acc[rt][ct][r] * scale + bv;
                    if (relu && v < 0.f) v = 0.f;
                    if (Cf) Cf[row * (long)ldc + col] = v;
                    else    Cb[row * (long)ldc + col] = (bf16)v;
                    rsum[ct] += v;
                    rsq[ct]  += v * v;
                }
            }
        }
    }

    if (colsum_ptr || bnsum_ptr) {
        __syncthreads();                  // all waves done reading Bs
        float* scr = (float*)Bs;          // 2560 floats; use 1024
#pragma unroll
        for (int ct = 0; ct < 8; ++ct) {
            float s = rsum[ct];
            s += __shfl_xor(s, 16);
            s += __shfl_xor(s, 32);
            float q = rsq[ct];
            q += __shfl_xor(q, 16);
            q += __shfl_xor(q, 32);
            if (quad == 0) {
                scr[wid * 128 + ct * 16 + m]       = s;
                scr[512 + wid * 128 + ct * 16 + m] = q;
            }
        }
        __syncthreads();
        if (tid < 128) {
            int col = colbase + tid;
            if (col < ncols) {
                float s = scr[tid] + scr[128 + tid] + scr[256 + tid] + scr[384 + tid];
                if (colsum_ptr && col < 200) atomicAdd(&colsum_ptr[col], s);
                if (bnsum_ptr) {
                    float q = scr[512 + tid] + scr[640 + tid] + scr[768 + tid] + scr[896 + tid];
                    atomicAdd(&bnsum_ptr[col], s);
                    atomicAdd(&bnsum_ptr[256 + col], q);
                }
            }
        }
    }
}

// ---------------- weight transpose + cast
__global__ void transpose_f2b(const float* __restrict__ in, int K, int ncols,
                              bf16* __restrict__ out, int Kd, int npad)
{
    long idx = (long)blockIdx.x * 256 + threadIdx.x;
    long total = (long)npad * Kd;
    if (idx >= total) return;
    int k = (int)(idx % Kd);
    int n = (int)(idx / Kd);
    float v = (k < K && n < ncols) ? in[(long)k * ncols + n] : 0.f;
    out[idx] = (bf16)v;
}

__global__ void transpose_M(const float* __restrict__ M, bf16* __restrict__ out)
{
    int idx = blockIdx.x * 256 + threadIdx.x;
    int k = idx & 127, n = idx >> 7;
    float v = (k < 100 && n < 100) ? M[k * 100 + n] : 0.f;
    out[idx] = (bf16)v;
}

__global__ void cast_f2b(const float* __restrict__ in, long total, bf16* __restrict__ out)
{
    long idx = (long)blockIdx.x * 256 + threadIdx.x;
    if (idx < total) out[idx] = (bf16)in[idx];
}

// ---------------- CSR build: hist + 3-phase parallel scan + scatter
__global__ void hist_kernel(const int* __restrict__ dst, int E, int* __restrict__ cnt)
{
    int e = blockIdx.x * 256 + threadIdx.x;
    if (e < E) atomicAdd(&cnt[dst[e]], 1);
}

__global__ __launch_bounds__(1024) void scanA_kernel(const int* __restrict__ cnt, int n,
                                                     int* __restrict__ csum)
{
    __shared__ int sdata[1024];
    int t = threadIdx.x;
    int i = blockIdx.x * 1024 + t;
    sdata[t] = (i < n) ? cnt[i] : 0;
    __syncthreads();
    for (int d = 512; d > 0; d >>= 1) {
        if (t < d) sdata[t] += sdata[t + d];
        __syncthreads();
    }
    if (t == 0) csum[blockIdx.x] = sdata[0];
}

__global__ void scanB_kernel(int* __restrict__ csum, int nchunks, int n, int* __restrict__ rowptr)
{
    if (threadIdx.x == 0) {
        int run = 0;
        for (int b = 0; b < nchunks; ++b) {
            int v = csum[b];
            csum[b] = run;
            run += v;
        }
        rowptr[n] = run;
    }
}

__global__ __launch_bounds__(1024) void scanC_kernel(const int* __restrict__ cnt, int n,
                                                     const int* __restrict__ csum,
                                                     int* __restrict__ rowptr,
                                                     int* __restrict__ cursor,
                                                     float* __restrict__ dis)
{
    __shared__ int sdata[1024];
    int t = threadIdx.x;
    int i = blockIdx.x * 1024 + t;
    int v = (i < n) ? cnt[i] : 0;
    sdata[t] = v;
    __syncthreads();
    for (int d = 1; d < 1024; d <<= 1) {
        int x = (t >= d) ? sdata[t - d] : 0;
        __syncthreads();
        sdata[t] += x;
        __syncthreads();
    }
    if (i < n) {
        int excl = csum[blockIdx.x] + sdata[t] - v;
        rowptr[i] = excl;
        cursor[i] = excl;
        dis[i] = rsqrtf((float)(v + 1));   // deg = in-degree + self-loop
    }
}

__global__ void scatter_kernel(const int* __restrict__ src, const int* __restrict__ dst,
                               int E, int* __restrict__ cursor, int* __restrict__ colidx)
{
    int e = blockIdx.x * 256 + threadIdx.x;
    if (e < E) {
        int d = dst[e];
        int pos = atomicAdd(&cursor[d], 1);
        colidx[pos] = src[e];
    }
}

// ---------------- GCN aggregation: one wave per dst node, bf16 h, 4x edge unroll
__global__ __launch_bounds__(256) void agg_kernel(
    const bf16* __restrict__ h, const int* __restrict__ rowptr,
    const int* __restrict__ colidx, const float* __restrict__ dis,
    const float* __restrict__ cb, bf16* __restrict__ out, int ldc, int R)
{
    int wid = threadIdx.x >> 6, lane = threadIdx.x & 63;
    int i = blockIdx.x * 4 + wid;
    if (i >= R) return;
    float disi = dis[i];
    bf16x4 hv = *(const bf16x4*)(h + (long)i * 256 + lane * 4);
    float acc[4];
#pragma unroll
    for (int j = 0; j < 4; ++j) acc[j] = (float)hv[j] * disi;  // self loop
    int e0 = rowptr[i], e1 = rowptr[i + 1];
    int e = e0;
    for (; e + 3 < e1; e += 4) {
        int s0 = colidx[e], s1 = colidx[e + 1], s2 = colidx[e + 2], s3 = colidx[e + 3];
        float w0 = dis[s0], w1 = dis[s1], w2 = dis[s2], w3 = dis[s3];
        bf16x4 h0 = *(const bf16x4*)(h + (long)s0 * 256 + lane * 4);
        bf16x4 h1 = *(const bf16x4*)(h + (long)s1 * 256 + lane * 4);
        bf16x4 h2 = *(const bf16x4*)(h + (long)s2 * 256 + lane * 4);
        bf16x4 h3 = *(const bf16x4*)(h + (long)s3 * 256 + lane * 4);
#pragma unroll
        for (int j = 0; j < 4; ++j)
            acc[j] += (float)h0[j] * w0 + (float)h1[j] * w1
                    + (float)h2[j] * w2 + (float)h3[j] * w3;
    }
    for (; e < e1; ++e) {
        int s = colidx[e];
        float w = dis[s];
        bf16x4 hs = *(const bf16x4*)(h + (long)s * 256 + lane * 4);
#pragma unroll
        for (int j = 0; j < 4; ++j) acc[j] += (float)hs[j] * w;
    }
    bf16x4 o;
#pragma unroll
    for (int j = 0; j < 4; ++j) {
        float v = acc[j] * disi + cb[lane * 4 + j];
        if (v < 0.f) v = 0.f;
        o[j] = (bf16)v;
    }
    *(bf16x4*)(out + (long)i * ldc + lane * 4) = o;
}

__global__ void nf_kernel(const float* __restrict__ cs, float* __restrict__ scale, int R)
{
    __shared__ float s[128];
    int t = threadIdx.x;
    float v = (t < 100) ? cs[t] * cs[100 + t] : 0.f;
    s[t] = v;
    __syncthreads();
    for (int d = 64; d > 0; d >>= 1) {
        if (t < d) s[t] += s[t + d];
        __syncthreads();
    }
    if (t == 0) scale[0] = 1.0f / (s[0] / (float)R + 1e-6f);
}

// ---------------- M = V^T Z via MFMA, two-stage, no atomics
#define VTZ_BLOCKS 192
__global__ __launch_bounds__(256) void vtz_mfma(const bf16* __restrict__ t, int ld, int R,
                                                float* __restrict__ Mpart)
{
    __shared__ bf16 Vt[112 * 72];
    __shared__ bf16 Zt[112 * 72];
    const int tid  = threadIdx.x;
    const int wid  = tid >> 6;
    const int lane = tid & 63;
    const int m    = lane & 15;
    const int quad = lane >> 4;

    for (int idx = tid; idx < 12 * 64; idx += 256) {
        int c = 100 + (idx >> 6), r = idx & 63;
        Vt[c * 72 + r] = (bf16)0.f;
        Zt[c * 72 + r] = (bf16)0.f;
    }

    f32x4 acc[2][7];
#pragma unroll
    for (int rt = 0; rt < 2; ++rt)
#pragma unroll
        for (int ct = 0; ct < 7; ++ct)
            acc[rt][ct] = f32x4{0.f, 0.f, 0.f, 0.f};

    for (long base = (long)blockIdx.x * 64; base < R; base += (long)gridDim.x * 64) {
        __syncthreads();
        for (int idx = tid; idx < 50 * 64; idx += 256) {
            int r = idx / 50, c2 = (idx - r * 50) * 2;
            bf16x2 v2 = bf16x2{(bf16)0.f, (bf16)0.f};
            bf16x2 z2 = bf16x2{(bf16)0.f, (bf16)0.f};
            if (base + r < R) {
                v2 = *(const bf16x2*)(t + (base + r) * ld + 100 + c2);
                z2 = *(const bf16x2*)(t + (base + r) * ld + 200 + c2);
            }
            Vt[c2 * 72 + r] = v2[0]; Vt[(c2 + 1) * 72 + r] = v2[1];
            Zt[c2 * 72 + r] = z2[0]; Zt[(c2 + 1) * 72 + r] = z2[1];
        }
        __syncthreads();
#pragma unroll
        for (int ks = 0; ks < 2; ++ks) {
            int k0 = ks * 32 + quad * 8;
            bf16x8 b[7];
#pragma unroll
            for (int ct = 0; ct < 7; ++ct)
                b[ct] = *(const bf16x8*)&Zt[(ct * 16 + m) * 72 + k0];
#pragma unroll
            for (int rt = 0; rt < 2; ++rt) {
                int tr = wid + rt * 4;
                if (tr >= 7) continue;
                bf16x8 a = *(const bf16x8*)&Vt[(tr * 16 + m) * 72 + k0];
#pragma unroll
                for (int ct = 0; ct < 7; ++ct)
                    acc[rt][ct] = __builtin_amdgcn_mfma_f32_16x16x32_bf16(a, b[ct], acc[rt][ct], 0, 0, 0);
            }
        }
    }

    float* out = Mpart + (long)blockIdx.x * 10000;
#pragma unroll
    for (int rt = 0; rt < 2; ++rt) {
        int tr = wid + rt * 4;
        if (tr >= 7) continue;
#pragma unroll
        for (int ct = 0; ct < 7; ++ct) {
            int b = ct * 16 + m;
            if (b >= 100) continue;
#pragma unroll
            for (int r = 0; r < 4; ++r) {
                int a = tr * 16 + quad * 4 + r;
                if (a < 100) out[a * 100 + b] = acc[rt][ct][r];
            }
        }
    }
}

__global__ void vtz_reduce(const float* __restrict__ Mpart, float* __restrict__ M)
{
    int idx = blockIdx.x * 256 + threadIdx.x;
    if (idx >= 10000) return;
    float s = 0.f;
    for (int b = 0; b < VTZ_BLOCKS; ++b) s += Mpart[(long)b * 10000 + idx];
    M[idx] = s;
}

// ---------------- batch norm finalize/apply (stats fused into readout GEMM)
__global__ void bn_finalize(const float* __restrict__ sums, const float* __restrict__ g,
                            const float* __restrict__ bt, int R, float* __restrict__ ab)
{
    int c = threadIdx.x;
    float mean = sums[c] / (float)R;
    float var  = sums[256 + c] / (float)R - mean * mean;
    if (var < 0.f) var = 0.f;
    float a = g[c] * rsqrtf(var + 1e-5f);
    ab[c] = a;
    ab[256 + c] = bt[c] - mean * a;
}

__global__ void bn_apply(const float* __restrict__ y, const float* __restrict__ ab,
                         int total, bf16* __restrict__ x)
{
    int idx = blockIdx.x * 256 + threadIdx.x;
    if (idx < total) {
        int c = idx & 255;
        x[idx] = (bf16)(y[idx] * ab[c] + ab[256 + c]);
    }
}

// =====================================================================================
extern "C" void kernel_launch(void* const* d_in, const int* in_sizes, int n_in,
                              void* d_out, int out_size, void* d_ws, size_t ws_size,
                              hipStream_t stream)
{
    (void)n_in; (void)out_size; (void)ws_size;
    const int N = in_sizes[0] / 128;       // 50000
    const int E = in_sizes[1] / 2;         // 800000

    const float* x0 = (const float*)d_in[0];
    const int*  ei   = (const int*)d_in[1];
    const int*  esrc = ei;
    const int*  edst = ei + E;
    const float *cw[3], *cbv[3], *aw[3], *abv[3], *rw[3], *rbv[3];
    for (int l = 0; l < 3; ++l) {
        cw[l]  = (const float*)d_in[2 + 6 * l];
        cbv[l] = (const float*)d_in[3 + 6 * l];
        aw[l]  = (const float*)d_in[4 + 6 * l];
        abv[l] = (const float*)d_in[5 + 6 * l];
        rw[l]  = (const float*)d_in[6 + 6 * l];
        rbv[l] = (const float*)d_in[7 + 6 * l];
    }
    const float* g[2]   = {(const float*)d_in[20], (const float*)d_in[22]};
    const float* btb[2] = {(const float*)d_in[21], (const float*)d_in[23]};

    // ---- workspace carve (~165.8 MB, below proven-good 166.5 MB) ----
    char* p = (char*)d_ws;
    auto carve = [&](size_t bytes) -> char* {
        char* r = p; p += (bytes + 255) & ~(size_t)255; return r;
    };
    int*   cnt    = (int*)carve((size_t)N * 4);
    int*   rowptr = (int*)carve((size_t)(N + 1) * 4);
    int*   cursor = (int*)carve((size_t)N * 4);
    int*   colidx = (int*)carve((size_t)E * 4);
    float* dis    = (float*)carve((size_t)N * 4);
    int*   csum   = (int*)carve(256 * 4);
    float* Mbuf   = (float*)carve(100 * 100 * 4);
    float* Mpart  = (float*)carve((size_t)VTZ_BLOCKS * 10000 * 4);
    float* csbuf  = (float*)carve(200 * 4);
    float* scale  = (float*)carve(256);
    float* bnsum  = (float*)carve(512 * 4);
    float* bnab   = (float*)carve(512 * 4);
    bf16*  MT     = (bf16*)carve(128 * 128 * 2);
    bf16*  cwT[3], *awT[3], *rwT[3];
    int din[3] = {128, 256, 256};
    int dou[3] = {256, 256, 128};
    for (int l = 0; l < 3; ++l) {
        cwT[l] = (bf16*)carve((size_t)256 * din[l] * 2);
        awT[l] = (bf16*)carve((size_t)512 * din[l] * 2);
        rwT[l] = (bf16*)carve((size_t)dou[l] * 480 * 2);
    }
    bf16*  xbf  = (bf16*)carve((size_t)N * 256 * 2);        // current x (bf16)
    float* hbuf = (float*)carve((size_t)N * 256 * 4);       // y (fp32); hb (bf16 h) aliases it
    bf16*  hb   = (bf16*)hbuf;                              // h bf16 — dead before y written
    bf16*  tbuf = (bf16*)carve((size_t)N * 300 * 2);        // U|V|Z (ld=300)
    bf16*  xcat = (bf16*)carve(((size_t)N * 456 + 32) * 2); // [res|T|xloc], ld=456

    // ---- CSR build (parallel scan) ----
    const int nchunks = (N + 1023) / 1024;
    hipMemsetAsync(cnt, 0, (size_t)N * 4, stream);
    hist_kernel<<<(E + 255) / 256, 256, 0, stream>>>(edst, E, cnt);
    scanA_kernel<<<nchunks, 1024, 0, stream>>>(cnt, N, csum);
    scanB_kernel<<<1, 64, 0, stream>>>(csum, nchunks, N, rowptr);
    scanC_kernel<<<nchunks, 1024, 0, stream>>>(cnt, N, csum, rowptr, cursor, dis);
    scatter_kernel<<<(E + 255) / 256, 256, 0, stream>>>(esrc, edst, E, cursor, colidx);

    // ---- weight transposes + x0 cast ----
    for (int l = 0; l < 3; ++l) {
        transpose_f2b<<<((long)256 * din[l] + 255) / 256, 256, 0, stream>>>(
            cw[l], din[l], 256, cwT[l], din[l], 256);
        transpose_f2b<<<((long)512 * din[l] + 255) / 256, 256, 0, stream>>>(
            aw[l], din[l], 400, awT[l], din[l], 512);
        transpose_f2b<<<((long)dou[l] * 480 + 255) / 256, 256, 0, stream>>>(
            rw[l], 456, dou[l], rwT[l], 480, dou[l]);
    }
    cast_f2b<<<((long)N * 128 + 255) / 256, 256, 0, stream>>>(x0, (long)N * 128, xbf);

    int lda = 128;
    const unsigned gx  = (unsigned)((N + 127) / 128);   // 128-row tiles
    const unsigned gx2 = (unsigned)((N + 255) / 256);   // 256-row tiles

    for (int l = 0; l < 3; ++l) {
        // 1) h = x @ cw -> hb (bf16; bias/relu deferred to agg)  [tall tile]
        gemm_mfma_t<<<dim3(gx2, 2), 256, 0, stream>>>(xbf, lda, cwT[l], din[l], nullptr,
                                                      hb, nullptr, 256, N, 256, 0, nullptr,
                                                      nullptr, nullptr);
        // 2) U|V|Z = relu(x @ aw[:,0:300] + ab[0:300]) -> tbuf, fused colsum of cols<200
        hipMemsetAsync(csbuf, 0, 200 * 4, stream);
        gemm_mfma_t<<<dim3(gx2, 3), 256, 0, stream>>>(xbf, lda, awT[l], din[l], abv[l],
                                                      tbuf, nullptr, 300, N, 300, 1, nullptr,
                                                      csbuf, nullptr);
        // 3) T = relu(x @ aw[:,300:400] + ab[300:]) -> xcat cols 100..199  [narrow]
        gemm_mfma<<<dim3(gx, 1), 256, 0, stream>>>(xbf, lda, awT[l] + (long)300 * din[l], din[l],
                                                   abv[l] + 300,
                                                   xcat + 100, nullptr, 456, N, 100, 1, nullptr);
        // 4) nf from fused colsums
        nf_kernel<<<1, 128, 0, stream>>>(csbuf, scale, N);
        // 5) M = V^T Z (MFMA two-stage) ; transpose/cast to MT
        vtz_mfma<<<VTZ_BLOCKS, 256, 0, stream>>>(tbuf, 300, N, Mpart);
        vtz_reduce<<<40, 256, 0, stream>>>(Mpart, Mbuf);
        transpose_M<<<64, 256, 0, stream>>>(Mbuf, MT);
        // 6) res = scale * (U @ M) -> xcat cols 0..99  [narrow]
        gemm_mfma<<<dim3(gx, 1), 256, 0, stream>>>(tbuf, 300, MT, 128, nullptr,
                                                   xcat, nullptr, 456, N, 100, 0, scale);
        // 7) x_local = relu(agg + cb) -> xcat cols 200..455
        agg_kernel<<<(N + 3) / 4, 256, 0, stream>>>(hb, rowptr, colidx, dis, cbv[l],
                                                    xcat + 200, 456, N);
        // 8) readout (Kd=480: cols 456..479 junk x zero weight rows = 0)
        if (l < 2) {
            hipMemsetAsync(bnsum, 0, 512 * 4, stream);
            gemm_mfma_t<<<dim3(gx2, 2), 256, 0, stream>>>(xcat, 456, rwT[l], 480, rbv[l],
                                                          nullptr, hbuf, 256, N, 256, 1, nullptr,
                                                          nullptr, bnsum);
            bn_finalize<<<1, 256, 0, stream>>>(bnsum, g[l], btb[l], N, bnab);
            bn_apply<<<((long)N * 256 + 255) / 256, 256, 0, stream>>>(hbuf, bnab, N * 256, xbf);
            lda = 256;
        } else {
            gemm_mfma<<<dim3(gx, 1), 256, 0, stream>>>(xcat, 456, rwT[l], 480, rbv[l],
                                                       nullptr, (float*)d_out, 128, N, 128, 0, nullptr);
        }
    }
}